// Round 1
// baseline (9548.861 us; speedup 1.0000x reference)
//
#include <hip/hip_runtime.h>
#include <math.h>

#define NB 16384
#define BERT_DIM 768
#define CONDD 64
#define INUMD 10
#define RNND 128
#define TDIFFN 200
#define SAMPLE_TN 50
#define TEMBD 64
#define TMAXN 64
#define DEN_IN 138      // INUM + COND + TEMB
#define DEN_IN_PAD 140
#define H0_IN 74        // COND + INUM
#define H0_IN_PAD 76

struct TsArg { float ts[SAMPLE_TN]; };

__device__ __forceinline__ float sigmoidf_(float v) { return 1.f / (1.f + expf(-v)); }

// ---------------- bert proj + layernorm ----------------
// one wave per row; lane j computes output col j (dot over 768), then wave-reduce LN
__global__ __launch_bounds__(256) void bert_ln_kernel(
    const float* __restrict__ bert, const float* __restrict__ bp_w,
    const float* __restrict__ bp_b, const float* __restrict__ ln_g,
    const float* __restrict__ ln_b, float* __restrict__ cond)
{
    __shared__ __align__(16) float row[4][BERT_DIM];
    int wave = threadIdx.x >> 6;
    int lane = threadIdx.x & 63;
    int r = blockIdx.x * 4 + wave;

    const float4* src = (const float4*)(bert + (size_t)r * BERT_DIM);
    float4* dst = (float4*)row[wave];
    #pragma unroll
    for (int j = 0; j < 3; ++j) dst[lane + j * 64] = src[lane + j * 64];
    __syncthreads();

    float acc = bp_b[lane];
    const float4* w4 = (const float4*)(bp_w + (size_t)lane * BERT_DIM);
    const float4* r4 = (const float4*)row[wave];
    for (int k = 0; k < BERT_DIM / 4; ++k) {
        float4 a = r4[k]; float4 w = w4[k];
        acc += a.x * w.x + a.y * w.y + a.z * w.z + a.w * w.w;
    }
    // LN over the 64 lanes
    float s = acc, s2 = acc * acc;
    #pragma unroll
    for (int off = 32; off; off >>= 1) { s += __shfl_xor(s, off); s2 += __shfl_xor(s2, off); }
    float mu = s * (1.f / 64.f);
    float var = s2 * (1.f / 64.f) - mu * mu;
    float inv = rsqrtf(var + 1e-5f);
    cond[(size_t)r * CONDD + lane] = (acc - mu) * inv * ln_g[lane] + ln_b[lane];
}

// ---------------- time embedding MLP (50x64, tiny) ----------------
__global__ __launch_bounds__(128) void te_kernel(
    const float* __restrict__ tp_w1, const float* __restrict__ tp_b1,
    const float* __restrict__ tp_w2, const float* __restrict__ tp_b2,
    float* __restrict__ te, TsArg tsarg)
{
    __shared__ float temb[TEMBD];
    __shared__ float h[TEMBD * 2];
    int s = blockIdx.x, t = threadIdx.x;
    if (t < 32) {
        float freq = expf(-logf(10000.f) * (float)t / 31.f);
        float e = tsarg.ts[s] * freq;
        temb[t] = sinf(e);
        temb[t + 32] = cosf(e);
    }
    __syncthreads();
    float a = tp_b1[t];
    for (int k = 0; k < TEMBD; ++k) a += temb[k] * tp_w1[t * TEMBD + k];
    h[t] = a * sigmoidf_(a);
    __syncthreads();
    if (t < TEMBD) {
        float a2 = tp_b2[t];
        for (int k = 0; k < 128; ++k) a2 += h[k] * tp_w2[t * 128 + k];
        te[s * TEMBD + t] = a2;
    }
}

// ---------------- pack padded weights (dn_w1 -> 140 cols, h0_w -> 76 cols) ----------------
__global__ void pack_kernel(const float* __restrict__ dn_w1, const float* __restrict__ h0_w,
                            float* __restrict__ w1p, float* __restrict__ h0wp)
{
    int i = blockIdx.x * 256 + threadIdx.x;
    if (i < 256 * DEN_IN_PAD) {
        int r = i / DEN_IN_PAD, c = i % DEN_IN_PAD;
        w1p[i] = (c < DEN_IN) ? dn_w1[r * DEN_IN + c] : 0.f;
    }
    if (i < 128 * H0_IN_PAD) {
        int r = i / H0_IN_PAD, c = i % H0_IN_PAD;
        h0wp[i] = (c < H0_IN) ? h0_w[r * H0_IN + c] : 0.f;
    }
}

// ---------------- fused DDPM denoiser step ----------------
// block = 256 threads, handles 16 rows. layer1/2: thread n = output col, 16 row accs,
// activations broadcast from LDS. layer3 + x-update: 160 threads.
__global__ __launch_bounds__(256) void ddpm_step_kernel(
    float* __restrict__ x, const float* __restrict__ cond, const float* __restrict__ te_s,
    const float* __restrict__ noise,
    const float* __restrict__ w1p, const float* __restrict__ b1,
    const float* __restrict__ w2, const float* __restrict__ b2,
    const float* __restrict__ w3, const float* __restrict__ b3,
    float c1, float c2, float sv)
{
    __shared__ __align__(16) float bufA[16][256];  // inp (140 used), later h2
    __shared__ __align__(16) float bufB[16][256];  // h1
    int tid = threadIdx.x;
    int row0 = blockIdx.x * 16;

    // stage inp = [x(10) | cond(64) | te(64) | pad(2)]
    if (tid < 160) { int r = tid / 10, i = tid % 10; bufA[r][i] = x[(size_t)(row0 + r) * INUMD + i]; }
    if (tid < 32)  { int r = tid >> 1, c = 138 + (tid & 1); bufA[r][c] = 0.f; }
    for (int idx = tid; idx < 16 * 64; idx += 256) {
        int r = idx >> 6, j = idx & 63;
        bufA[r][10 + j] = cond[(size_t)(row0 + r) * CONDD + j];
    }
    for (int idx = tid; idx < 16 * 64; idx += 256) {
        int r = idx >> 6, j = idx & 63;
        bufA[r][74 + j] = te_s[j];
    }
    __syncthreads();

    float acc[16];
    // layer 1: 138(140) -> 256, silu
    {
        float b = b1[tid];
        #pragma unroll
        for (int r = 0; r < 16; ++r) acc[r] = b;
        const float4* wrow = (const float4*)(w1p + (size_t)tid * DEN_IN_PAD);
        for (int k = 0; k < DEN_IN_PAD / 4; ++k) {
            float4 w = wrow[k];
            #pragma unroll
            for (int r = 0; r < 16; ++r) {
                float4 a = ((const float4*)bufA[r])[k];
                acc[r] += a.x * w.x + a.y * w.y + a.z * w.z + a.w * w.w;
            }
        }
        #pragma unroll
        for (int r = 0; r < 16; ++r) { float v = acc[r]; bufB[r][tid] = v * sigmoidf_(v); }
    }
    __syncthreads();
    // layer 2: 256 -> 256, silu (write into bufA; all bufA reads finished before last barrier)
    {
        float b = b2[tid];
        #pragma unroll
        for (int r = 0; r < 16; ++r) acc[r] = b;
        const float4* wrow = (const float4*)(w2 + (size_t)tid * 256);
        for (int k = 0; k < 64; ++k) {
            float4 w = wrow[k];
            #pragma unroll
            for (int r = 0; r < 16; ++r) {
                float4 a = ((const float4*)bufB[r])[k];
                acc[r] += a.x * w.x + a.y * w.y + a.z * w.z + a.w * w.w;
            }
        }
        __syncthreads();
        #pragma unroll
        for (int r = 0; r < 16; ++r) { float v = acc[r]; bufA[r][tid] = v * sigmoidf_(v); }
    }
    __syncthreads();
    // layer 3: 256 -> 10, then ancestral update
    if (tid < 160) {
        int r = tid / 10, o = tid % 10;
        float a = b3[o];
        const float4* wrow = (const float4*)(w3 + (size_t)o * 256);
        for (int k = 0; k < 64; ++k) {
            float4 w = wrow[k];
            float4 hh = ((const float4*)bufA[r])[k];
            a += hh.x * w.x + hh.y * w.y + hh.z * w.z + hh.w * w.w;
        }
        size_t gi = (size_t)(row0 + r) * INUMD + o;
        float xold = x[gi];
        x[gi] = c1 * a + c2 * xold + sv * noise[gi];
    }
}

// ---------------- seq MLP + h0 init ----------------
__global__ __launch_bounds__(128) void h0_kernel(
    const float* __restrict__ x0, const float* __restrict__ cond,
    const float* __restrict__ sf_w1, const float* __restrict__ sf_b1,
    const float* __restrict__ sf_w2, const float* __restrict__ sf_b2,
    const float* __restrict__ sf_w3, const float* __restrict__ sf_b3,
    const float* __restrict__ h0wp, const float* __restrict__ h0_b,
    float* __restrict__ h, float* __restrict__ out_x0)
{
    __shared__ float xr[INUMD];
    __shared__ float s1[20], s2[20];
    __shared__ __align__(16) float in2[H0_IN_PAD];
    int r = blockIdx.x, t = threadIdx.x;
    if (t < INUMD) { float v = x0[(size_t)r * INUMD + t]; xr[t] = v; out_x0[(size_t)r * INUMD + t] = v; }
    if (t < CONDD) in2[t] = cond[(size_t)r * CONDD + t];
    if (t >= 120 && t < 122) in2[74 + (t - 120)] = 0.f;
    __syncthreads();
    if (t < 20) {
        float a = sf_b1[t];
        for (int k = 0; k < 10; ++k) a += xr[k] * sf_w1[t * 10 + k];
        s1[t] = fmaxf(a, 0.f);
    }
    __syncthreads();
    if (t < 20) {
        float a = sf_b2[t];
        for (int k = 0; k < 20; ++k) a += s1[k] * sf_w2[t * 20 + k];
        s2[t] = fmaxf(a, 0.f);
    }
    __syncthreads();
    if (t < 10) {
        float a = sf_b3[t];
        for (int k = 0; k < 20; ++k) a += s2[k] * sf_w3[t * 20 + k];
        in2[CONDD + t] = a;
    }
    __syncthreads();
    {
        float a = h0_b[t];
        const float4* w4 = (const float4*)(h0wp + (size_t)t * H0_IN_PAD);
        for (int k = 0; k < H0_IN_PAD / 4; ++k) {
            float4 w = w4[k];
            float4 v = ((const float4*)in2)[k];
            a += v.x * w.x + v.y * w.y + v.z * w.z + v.w * w.w;
        }
        h[(size_t)r * RNND + t] = tanhf(a);
    }
}

// ---------------- fused GRU step ----------------
// block = 384 threads, 16 rows. thread t computes gh col t for all rows.
__global__ __launch_bounds__(384) void gru_step_kernel(
    float* __restrict__ h, const float* __restrict__ times,
    const float* __restrict__ gru_wi, const float* __restrict__ gru_bi,
    const float* __restrict__ gru_wh, const float* __restrict__ gru_bh,
    const float* __restrict__ hd_w, const float* __restrict__ hd_b,
    float* __restrict__ pred, float* __restrict__ stopl, int step)
{
    __shared__ __align__(16) float hl[16][RNND];
    __shared__ __align__(16) float gh[16][3 * RNND];
    __shared__ float xin[16];
    int t = threadIdx.x;
    int row0 = blockIdx.x * 16;

    for (int idx = t; idx < 16 * RNND; idx += 384) {
        int r = idx >> 7, j = idx & 127;
        hl[r][j] = h[(size_t)(row0 + r) * RNND + j];
    }
    if (t < 16) {
        int r = row0 + t;
        float v;
        if (step == 0) v = 0.f;
        else if (step == 1) v = times[(size_t)r * TMAXN];
        else v = times[(size_t)r * TMAXN + step - 1] - times[(size_t)r * TMAXN + step - 2];
        xin[t] = v;
    }
    __syncthreads();

    {
        float acc[16];
        float b = gru_bh[t];
        #pragma unroll
        for (int r = 0; r < 16; ++r) acc[r] = b;
        const float4* wrow = (const float4*)(gru_wh + (size_t)t * RNND);
        for (int k = 0; k < RNND / 4; ++k) {
            float4 w = wrow[k];
            #pragma unroll
            for (int r = 0; r < 16; ++r) {
                float4 a = ((const float4*)hl[r])[k];
                acc[r] += a.x * w.x + a.y * w.y + a.z * w.z + a.w * w.w;
            }
        }
        #pragma unroll
        for (int r = 0; r < 16; ++r) gh[r][t] = acc[r];
    }
    __syncthreads();

    for (int idx = t; idx < 16 * RNND; idx += 384) {
        int r = idx >> 7, j = idx & 127;
        float xv = xin[r];
        float gir = xv * gru_wi[j]       + gru_bi[j];
        float giz = xv * gru_wi[128 + j] + gru_bi[128 + j];
        float gin = xv * gru_wi[256 + j] + gru_bi[256 + j];
        float rr = sigmoidf_(gir + gh[r][j]);
        float zz = sigmoidf_(giz + gh[r][128 + j]);
        float nn = tanhf(gin + rr * gh[r][256 + j]);
        float hn = (1.f - zz) * nn + zz * hl[r][j];
        hl[r][j] = hn;
        h[(size_t)(row0 + r) * RNND + j] = hn;
    }
    __syncthreads();

    if (t < 32) {
        int r = t >> 1, o = t & 1;
        float a = hd_b[o];
        const float4* w4 = (const float4*)(hd_w + (size_t)o * RNND);
        for (int k = 0; k < RNND / 4; ++k) {
            float4 w = w4[k];
            float4 v = ((const float4*)hl[r])[k];
            a += v.x * w.x + v.y * w.y + v.z * w.z + v.w * w.w;
        }
        float* dstp = o ? stopl : pred;
        dstp[(size_t)(row0 + r) * (TMAXN + 1) + step] = a;
    }
}

extern "C" void kernel_launch(void* const* d_in, const int* in_sizes, int n_in,
                              void* d_out, int out_size, void* d_ws, size_t ws_size,
                              hipStream_t stream)
{
    const float* bert       = (const float*)d_in[0];
    const float* times      = (const float*)d_in[1];
    const float* init_noise = (const float*)d_in[2];
    const float* step_noise = (const float*)d_in[3];
    const float* bp_w  = (const float*)d_in[4];
    const float* bp_b  = (const float*)d_in[5];
    const float* ln_g  = (const float*)d_in[6];
    const float* ln_b  = (const float*)d_in[7];
    const float* tp_w1 = (const float*)d_in[8];
    const float* tp_b1 = (const float*)d_in[9];
    const float* tp_w2 = (const float*)d_in[10];
    const float* tp_b2 = (const float*)d_in[11];
    const float* dn_w1 = (const float*)d_in[12];
    const float* dn_b1 = (const float*)d_in[13];
    const float* dn_w2 = (const float*)d_in[14];
    const float* dn_b2 = (const float*)d_in[15];
    const float* dn_w3 = (const float*)d_in[16];
    const float* dn_b3 = (const float*)d_in[17];
    const float* sf_w1 = (const float*)d_in[18];
    const float* sf_b1 = (const float*)d_in[19];
    const float* sf_w2 = (const float*)d_in[20];
    const float* sf_b2 = (const float*)d_in[21];
    const float* sf_w3 = (const float*)d_in[22];
    const float* sf_b3 = (const float*)d_in[23];
    const float* h0_w  = (const float*)d_in[24];
    const float* h0_b  = (const float*)d_in[25];
    const float* gru_wi = (const float*)d_in[26];
    const float* gru_bi = (const float*)d_in[27];
    const float* gru_wh = (const float*)d_in[28];
    const float* gru_bh = (const float*)d_in[29];
    const float* hd_w   = (const float*)d_in[30];
    const float* hd_b   = (const float*)d_in[31];

    float* ws   = (float*)d_ws;
    float* cond = ws;                              // B*64
    float* x    = cond + (size_t)NB * CONDD;       // B*10
    float* te   = x + (size_t)NB * INUMD;          // 50*64
    float* h    = te + SAMPLE_TN * TEMBD;          // B*128
    float* w1p  = h + (size_t)NB * RNND;           // 256*140
    float* h0wp = w1p + 256 * DEN_IN_PAD;          // 128*76

    // ---- host-side diffusion schedule (double, matches numpy) ----
    double ab[TDIFFN + 1];
    for (int i = 0; i <= TDIFFN; ++i) {
        double xx = (double)i / (double)TDIFFN;
        double v = cos((xx + 0.008) / 1.008 * M_PI * 0.5);
        ab[i] = v * v;
    }
    double ab0 = ab[0];
    for (int i = 0; i <= TDIFFN; ++i) ab[i] /= ab0;
    double betas[TDIFFN], alphas[TDIFFN], abar[TDIFFN];
    double cp = 1.0;
    for (int i = 0; i < TDIFFN; ++i) {
        double b = 1.0 - ab[i + 1] / ab[i];
        if (b > 0.9999) b = 0.9999;
        betas[i] = b; alphas[i] = 1.0 - b;
        cp *= alphas[i]; abar[i] = cp;
    }
    float c1f[SAMPLE_TN], c2f[SAMPLE_TN], svf[SAMPLE_TN];
    TsArg tsarg;
    for (int s = 0; s < SAMPLE_TN; ++s) {
        int tt = TDIFFN - 1 - 4 * s;   // 199, 195, ..., 3
        double abt = abar[tt];
        double abp = (tt > 0) ? abar[tt - 1] : 1.0;
        double beta = betas[tt];
        double c1 = sqrt(abp) * beta / (1.0 - abt);
        double c2 = sqrt(alphas[tt]) * (1.0 - abp) / (1.0 - abt);
        double var = (1.0 - abp) / (1.0 - abt) * beta;
        double sv = (tt > 0) ? sqrt(var) : 0.0;
        c1f[s] = (float)c1; c2f[s] = (float)c2; svf[s] = (float)sv;
        tsarg.ts[s] = (float)tt;
    }

    // ---- pipeline ----
    hipMemcpyAsync(x, init_noise, (size_t)NB * INUMD * sizeof(float),
                   hipMemcpyDeviceToDevice, stream);
    bert_ln_kernel<<<NB / 4, 256, 0, stream>>>(bert, bp_w, bp_b, ln_g, ln_b, cond);
    te_kernel<<<SAMPLE_TN, 128, 0, stream>>>(tp_w1, tp_b1, tp_w2, tp_b2, te, tsarg);
    pack_kernel<<<140, 256, 0, stream>>>(dn_w1, h0_w, w1p, h0wp);

    for (int s = 0; s < SAMPLE_TN; ++s) {
        ddpm_step_kernel<<<NB / 16, 256, 0, stream>>>(
            x, cond, te + s * TEMBD, step_noise + (size_t)s * NB * INUMD,
            w1p, dn_b1, dn_w2, dn_b2, dn_w3, dn_b3,
            c1f[s], c2f[s], svf[s]);
    }

    float* out    = (float*)d_out;
    float* out_x0 = out;
    float* pred   = out + (size_t)NB * INUMD;
    float* stopl  = pred + (size_t)NB * (TMAXN + 1);

    h0_kernel<<<NB, 128, 0, stream>>>(x, cond, sf_w1, sf_b1, sf_w2, sf_b2,
                                      sf_w3, sf_b3, h0wp, h0_b, h, out_x0);

    for (int i = 0; i <= TMAXN; ++i) {
        gru_step_kernel<<<NB / 16, 384, 0, stream>>>(
            h, times, gru_wi, gru_bi, gru_wh, gru_bh, hd_w, hd_b, pred, stopl, i);
    }
}

// Round 3
// 4000.438 us; speedup vs baseline: 2.3870x; 2.3870x over previous
//
#include <hip/hip_runtime.h>
#include <math.h>

typedef float f4 __attribute__((ext_vector_type(4)));

#define NB 16384
#define BERT_DIM 768
#define CONDD 64
#define INUMD 10
#define RNND 128
#define TDIFFN 200
#define SAMPLE_TN 50
#define TEMBD 64
#define TMAXN 64

struct Sched { float c1[SAMPLE_TN], c2[SAMPLE_TN], sv[SAMPLE_TN], ts[SAMPLE_TN]; };

__device__ __forceinline__ float fsig(float v)  { return __builtin_amdgcn_rcpf(1.f + __expf(-v)); }
__device__ __forceinline__ float ftanh(float v) { return 1.f - 2.f * __builtin_amdgcn_rcpf(1.f + __expf(2.f * v)); }
__device__ __forceinline__ float fsilu(float v) { return v * fsig(v); }

// ---------------- pack: transposed / padded weights ----------------
__global__ __launch_bounds__(256) void pack_kernel(
    const float* __restrict__ dn_w1, const float* __restrict__ dn_w2,
    const float* __restrict__ gru_wh, const float* __restrict__ h0_w,
    const float* __restrict__ bp_w,
    float* __restrict__ w1ct, float* __restrict__ w1xt, float* __restrict__ w2t,
    float* __restrict__ wht, float* __restrict__ h0wp, float* __restrict__ bp_wt)
{
    int idx = blockIdx.x * 256 + threadIdx.x;   // 0..65535
    if (idx < 16384) { int k = idx >> 8, n = idx & 255; w1ct[idx] = dn_w1[n * 138 + 10 + k]; }
    if (idx < 2560)  { int k = idx >> 8, n = idx & 255; w1xt[idx] = dn_w1[n * 138 + k]; }
    if (idx < 65536) { int k = idx >> 8, n = idx & 255; w2t[idx]  = dn_w2[n * 256 + k]; }
    if (idx < 49152) { int k = idx / 384, n = idx % 384; wht[idx] = gru_wh[n * 128 + k]; }
    if (idx < 9728)  { int r = idx / 76, c = idx % 76; h0wp[idx] = (c < 74) ? h0_w[r * 74 + c] : 0.f; }
    if (idx < 49152) { int k = idx / 64, n = idx % 64; bp_wt[idx] = bp_w[n * 768 + k]; }
}

// ---------------- bert proj + LN (tiled GEMM, 64 rows/block) ----------------
__global__ __launch_bounds__(512, 1) void bert2_kernel(
    const float* __restrict__ bert, const float* __restrict__ bp_wt,
    const float* __restrict__ bp_b, const float* __restrict__ ln_g,
    const float* __restrict__ ln_b, float* __restrict__ cond)
{
    __shared__ float At[64][68];
    __shared__ float outs[64][68];
    int tid = threadIdx.x;
    int row0 = blockIdx.x * 64;
    int cg = tid & 15, rg = tid >> 4;          // cols cg*4.., rows rg*2..

    f4 acc[2];
    acc[0] = (f4)0.f; acc[1] = (f4)0.f;
    for (int p = 0; p < 12; ++p) {
        // stage A panel [64 rows][64 k]
        for (int u = tid; u < 64 * 16; u += 512) {
            int row = u >> 4, q = u & 15;
            *(f4*)(&At[row][q * 4]) = *(const f4*)(bert + (size_t)(row0 + row) * BERT_DIM + p * 64 + q * 4);
        }
        __syncthreads();
        for (int kq = 0; kq < 16; ++kq) {
            int k = p * 64 + kq * 4;
            f4 w0 = *(const f4*)(bp_wt + (size_t)(k + 0) * 64 + cg * 4);
            f4 w1 = *(const f4*)(bp_wt + (size_t)(k + 1) * 64 + cg * 4);
            f4 w2 = *(const f4*)(bp_wt + (size_t)(k + 2) * 64 + cg * 4);
            f4 w3 = *(const f4*)(bp_wt + (size_t)(k + 3) * 64 + cg * 4);
            #pragma unroll
            for (int i = 0; i < 2; ++i) {
                f4 a = *(const f4*)(&At[rg * 2 + i][kq * 4]);
                acc[i] += a[0] * w0 + a[1] * w1 + a[2] * w2 + a[3] * w3;
            }
        }
        __syncthreads();
    }
    f4 bb = *(const f4*)(bp_b + cg * 4);
    #pragma unroll
    for (int i = 0; i < 2; ++i) {
        f4 v = acc[i] + bb;
        *(f4*)(&outs[rg * 2 + i][cg * 4]) = v;
    }
    __syncthreads();
    // LN: 64 rows x 8 segs of 8
    {
        int row = tid >> 3, seg = tid & 7;
        f4 v0 = *(const f4*)(&outs[row][seg * 8]);
        f4 v1 = *(const f4*)(&outs[row][seg * 8 + 4]);
        float s = v0[0]+v0[1]+v0[2]+v0[3]+v1[0]+v1[1]+v1[2]+v1[3];
        float s2 = v0[0]*v0[0]+v0[1]*v0[1]+v0[2]*v0[2]+v0[3]*v0[3]
                 + v1[0]*v1[0]+v1[1]*v1[1]+v1[2]*v1[2]+v1[3]*v1[3];
        #pragma unroll
        for (int off = 1; off < 8; off <<= 1) { s += __shfl_xor(s, off); s2 += __shfl_xor(s2, off); }
        float mu = s * (1.f / 64.f);
        float var = s2 * (1.f / 64.f) - mu * mu;
        float inv = rsqrtf(var + 1e-5f);
        f4 g0 = *(const f4*)(ln_g + seg * 8), g1 = *(const f4*)(ln_g + seg * 8 + 4);
        f4 b0 = *(const f4*)(ln_b + seg * 8), b1 = *(const f4*)(ln_b + seg * 8 + 4);
        f4 o0, o1;
        #pragma unroll
        for (int j = 0; j < 4; ++j) {
            o0[j] = (v0[j] - mu) * inv * g0[j] + b0[j];
            o1[j] = (v1[j] - mu) * inv * g1[j] + b1[j];
        }
        float* dst = cond + (size_t)(row0 + row) * CONDD + seg * 8;
        *(f4*)dst = o0; *(f4*)(dst + 4) = o1;
    }
}

// ---------------- time embedding MLP ----------------
__global__ __launch_bounds__(128) void te_kernel(
    const float* __restrict__ tp_w1, const float* __restrict__ tp_b1,
    const float* __restrict__ tp_w2, const float* __restrict__ tp_b2,
    float* __restrict__ te, Sched sc)
{
    __shared__ float temb[TEMBD];
    __shared__ float h[TEMBD * 2];
    int s = blockIdx.x, t = threadIdx.x;
    if (t < 32) {
        float freq = expf(-logf(10000.f) * (float)t / 31.f);
        float e = sc.ts[s] * freq;
        temb[t] = sinf(e);
        temb[t + 32] = cosf(e);
    }
    __syncthreads();
    float a = tp_b1[t];
    for (int k = 0; k < TEMBD; ++k) a += temb[k] * tp_w1[t * TEMBD + k];
    h[t] = a * (1.f / (1.f + expf(-a)));
    __syncthreads();
    if (t < TEMBD) {
        float a2 = tp_b2[t];
        for (int k = 0; k < 128; ++k) a2 += h[k] * tp_w2[t * 128 + k];
        te[s * TEMBD + t] = a2;
    }
}

// ---------------- b1eff[s][n] = b1[n] + sum_k te[s][k]*w1[n][74+k] ----------------
__global__ __launch_bounds__(256) void b1eff_kernel(
    const float* __restrict__ te, const float* __restrict__ dn_w1,
    const float* __restrict__ dn_b1, float* __restrict__ b1eff)
{
    __shared__ float tes[64];
    int s = blockIdx.x, n = threadIdx.x;
    if (n < 64) tes[n] = te[s * 64 + n];
    __syncthreads();
    float a = dn_b1[n];
    for (int k = 0; k < 64; ++k) a += tes[k] * dn_w1[n * 138 + 74 + k];
    b1eff[s * 256 + n] = a;
}

// ---------------- single-kernel DDPM: 50 steps in-kernel ----------------
#define DR 32
__global__ __launch_bounds__(256, 2) void ddpm_all_kernel(
    const float* __restrict__ x_init, const float* __restrict__ cond,
    const float* __restrict__ noise,
    const float* __restrict__ w1ct, const float* __restrict__ w1xt,
    const float* __restrict__ b1eff, const float* __restrict__ w2t,
    const float* __restrict__ b2, const float* __restrict__ w3g,
    const float* __restrict__ b3, Sched sc, float* __restrict__ out_x0)
{
    __shared__ float cond1[DR][260];
    __shared__ float hbuf[DR][260];
    __shared__ float w3s[10 * 256];
    __shared__ float xbuf[DR][12];
    int tid = threadIdx.x;
    int row0 = blockIdx.x * DR;
    int rg = tid & 3, cg = tid >> 2;           // rows rg*8.., cols cg*4..

    // stage cond into hbuf-alias, x, w3
    float* condl = &hbuf[0][0];                // [32][64]
    for (int u = tid; u < DR * 16; u += 256) {
        int r = u >> 4, q = u & 15;
        *(f4*)(condl + r * 64 + q * 4) = *(const f4*)(cond + (size_t)(row0 + r) * CONDD + q * 4);
    }
    for (int u = tid; u < 2560; u += 256) w3s[u] = w3g[u];
    for (int u = tid; u < DR * 10; u += 256) {             // FIX: was if(tid<320) in 256-thread block
        int r = u / 10, k = u % 10;
        xbuf[r][k] = x_init[(size_t)(row0 + r) * INUMD + k];
    }
    __syncthreads();

    // cond1 = cond @ w1c^T  (K=64)
    {
        f4 acc[8];
        #pragma unroll
        for (int i = 0; i < 8; ++i) acc[i] = (f4)0.f;
        for (int kq = 0; kq < 16; ++kq) {
            int k = kq * 4;
            f4 w0 = *(const f4*)(w1ct + (k + 0) * 256 + cg * 4);
            f4 w1 = *(const f4*)(w1ct + (k + 1) * 256 + cg * 4);
            f4 w2 = *(const f4*)(w1ct + (k + 2) * 256 + cg * 4);
            f4 w3 = *(const f4*)(w1ct + (k + 3) * 256 + cg * 4);
            #pragma unroll
            for (int i = 0; i < 8; ++i) {
                f4 a = *(const f4*)(condl + (rg * 8 + i) * 64 + k);
                acc[i] += a[0] * w0 + a[1] * w1 + a[2] * w2 + a[3] * w3;
            }
        }
        __syncthreads();   // condl reads done before hbuf reuse; cond1 writes begin
        #pragma unroll
        for (int i = 0; i < 8; ++i) *(f4*)(&cond1[rg * 8 + i][cg * 4]) = acc[i];
    }
    __syncthreads();

    #pragma unroll 1
    for (int s = 0; s < SAMPLE_TN; ++s) {
        // ---- layer1: K=10 over x, plus cond1 + b1eff ----
        {
            f4 be = *(const f4*)(b1eff + s * 256 + cg * 4);
            f4 acc[8];
            #pragma unroll
            for (int i = 0; i < 8; ++i) acc[i] = *(const f4*)(&cond1[rg * 8 + i][cg * 4]) + be;
            #pragma unroll
            for (int k = 0; k < 10; ++k) {
                f4 w = *(const f4*)(w1xt + k * 256 + cg * 4);
                #pragma unroll
                for (int i = 0; i < 8; ++i) acc[i] += xbuf[rg * 8 + i][k] * w;
            }
            #pragma unroll
            for (int i = 0; i < 8; ++i) {
                f4 v = acc[i], o;
                #pragma unroll
                for (int j = 0; j < 4; ++j) o[j] = fsilu(v[j]);
                *(f4*)(&hbuf[rg * 8 + i][cg * 4]) = o;
            }
        }
        __syncthreads();
        // ---- layer2: K=256 ----
        {
            f4 bv = *(const f4*)(b2 + cg * 4);
            f4 acc[8];
            #pragma unroll
            for (int i = 0; i < 8; ++i) acc[i] = bv;
            for (int kq = 0; kq < 64; ++kq) {
                int k = kq * 4;
                f4 w0 = *(const f4*)(w2t + (k + 0) * 256 + cg * 4);
                f4 w1 = *(const f4*)(w2t + (k + 1) * 256 + cg * 4);
                f4 w2 = *(const f4*)(w2t + (k + 2) * 256 + cg * 4);
                f4 w3 = *(const f4*)(w2t + (k + 3) * 256 + cg * 4);
                f4 a[8];
                #pragma unroll
                for (int i = 0; i < 8; ++i) a[i] = *(const f4*)(&hbuf[rg * 8 + i][k]);
                #pragma unroll
                for (int i = 0; i < 8; ++i)
                    acc[i] += a[i][0] * w0 + a[i][1] * w1 + a[i][2] * w2 + a[i][3] * w3;
            }
            __syncthreads();   // all hbuf reads done
            #pragma unroll
            for (int i = 0; i < 8; ++i) {
                f4 v = acc[i], o;
                #pragma unroll
                for (int j = 0; j < 4; ++j) o[j] = fsilu(v[j]);
                *(f4*)(&hbuf[rg * 8 + i][cg * 4]) = o;
            }
        }
        __syncthreads();
        // ---- layer3 (N=10) + ancestral update ----
        {
            int r3 = tid >> 3, seg = tid & 7;
            float p[10];
            #pragma unroll
            for (int o = 0; o < 10; ++o) p[o] = 0.f;
            #pragma unroll
            for (int kq = 0; kq < 8; ++kq) {
                int k = seg * 32 + kq * 4;
                f4 a = *(const f4*)(&hbuf[r3][k]);
                #pragma unroll
                for (int o = 0; o < 10; ++o) {
                    f4 w = *(const f4*)(&w3s[o * 256 + k]);
                    p[o] += a[0] * w[0] + a[1] * w[1] + a[2] * w[2] + a[3] * w[3];
                }
            }
            #pragma unroll
            for (int o = 0; o < 10; ++o) {
                p[o] += __shfl_xor(p[o], 1);
                p[o] += __shfl_xor(p[o], 2);
                p[o] += __shfl_xor(p[o], 4);
            }
            if (seg == 0) {
                float c1 = sc.c1[s], c2 = sc.c2[s], sv = sc.sv[s];
                const float* nz = noise + ((size_t)s * NB + row0 + r3) * INUMD;
                #pragma unroll
                for (int o = 0; o < 10; ++o) {
                    float x0p = p[o] + b3[o];
                    xbuf[r3][o] = c1 * x0p + c2 * xbuf[r3][o] + sv * nz[o];
                }
            }
        }
        __syncthreads();
    }
    for (int u = tid; u < DR * 10; u += 256) {             // FIX: was if(tid<320) in 256-thread block
        int r = u / 10, k = u % 10;
        out_x0[(size_t)(row0 + r) * INUMD + k] = xbuf[r][k];
    }
}

// ---------------- single-kernel GRU: seq-MLP + h0 + 65 steps ----------------
__global__ __launch_bounds__(384, 2) void gru_all_kernel(
    const float* __restrict__ x0, const float* __restrict__ cond,
    const float* __restrict__ times,
    const float* __restrict__ sf_w1, const float* __restrict__ sf_b1,
    const float* __restrict__ sf_w2, const float* __restrict__ sf_b2,
    const float* __restrict__ sf_w3, const float* __restrict__ sf_b3,
    const float* __restrict__ h0wp, const float* __restrict__ h0_b,
    const float* __restrict__ wht, const float* __restrict__ gru_bh,
    const float* __restrict__ gru_wi, const float* __restrict__ gru_bi,
    const float* __restrict__ hd_w, const float* __restrict__ hd_b,
    float* __restrict__ pred, float* __restrict__ stopl)
{
    __shared__ float hl[32][128];
    __shared__ float gh[32][384];
    __shared__ float dl[32][66];
    __shared__ float wis[384], bis[384], bhs[384];
    int tid = threadIdx.x;
    int row0 = blockIdx.x * 32;

    wis[tid] = gru_wi[tid]; bis[tid] = gru_bi[tid]; bhs[tid] = gru_bh[tid];

    // deltas from times (staged in gh region)
    float* tb = &gh[0][0];                     // [32][64]
    for (int idx = tid; idx < 32 * 64; idx += 384) {
        int r = idx >> 6, k = idx & 63;
        tb[idx] = times[(size_t)(row0 + r) * TMAXN + k];
    }
    __syncthreads();
    float dtmp[6]; int dcnt = 0;
    for (int idx = tid; idx < 32 * 65; idx += 384) {
        int r = idx / 65, i = idx % 65;
        float v;
        if (i == 0) v = 0.f;
        else if (i == 1) v = tb[r * 64];
        else v = tb[r * 64 + i - 1] - tb[r * 64 + i - 2];
        dtmp[dcnt++] = v;
    }
    __syncthreads();
    dcnt = 0;
    for (int idx = tid; idx < 32 * 65; idx += 384) {
        int r = idx / 65, i = idx % 65;
        dl[r][i] = dtmp[dcnt++];
    }
    // build in2 = [cond | seq_emb | pad] overlaid on gh
    float* in2 = &gh[0][0];                    // [32][76]
    float* sbuf = in2 + 32 * 76;               // [32][44]
    __syncthreads();
    for (int idx = tid; idx < 32 * 64; idx += 384) {
        int r = idx >> 6, k = idx & 63;
        in2[r * 76 + k] = cond[(size_t)(row0 + r) * CONDD + k];
    }
    for (int idx = tid; idx < 320; idx += 384) {
        int r = idx / 10, k = idx % 10;
        in2[r * 76 + 64 + k] = x0[(size_t)(row0 + r) * INUMD + k];
    }
    if (tid < 64) { int r = tid >> 1; in2[r * 76 + 74 + (tid & 1)] = 0.f; }
    __syncthreads();
    for (int idx = tid; idx < 640; idx += 384) {
        int r = idx / 20, j = idx % 20;
        float a = sf_b1[j];
        for (int k = 0; k < 10; ++k) a += in2[r * 76 + 64 + k] * sf_w1[j * 10 + k];
        sbuf[r * 44 + j] = fmaxf(a, 0.f);
    }
    __syncthreads();
    for (int idx = tid; idx < 640; idx += 384) {
        int r = idx / 20, j = idx % 20;
        float a = sf_b2[j];
        for (int k = 0; k < 20; ++k) a += sbuf[r * 44 + k] * sf_w2[j * 20 + k];
        sbuf[r * 44 + 22 + j] = fmaxf(a, 0.f);
    }
    __syncthreads();
    for (int idx = tid; idx < 320; idx += 384) {
        int r = idx / 10, j = idx % 10;
        float a = sf_b3[j];
        for (int k = 0; k < 20; ++k) a += sbuf[r * 44 + 22 + k] * sf_w3[j * 20 + k];
        in2[r * 76 + 64 + j] = a;
    }
    __syncthreads();
    // h0 = tanh(in2 @ h0wp^T)
    for (int idx = tid; idx < 4096; idx += 384) {
        int r = idx >> 7, j = idx & 127;
        float a = h0_b[j];
        const f4* wr = (const f4*)(h0wp + j * 76);
        const f4* iv = (const f4*)(in2 + r * 76);
        #pragma unroll
        for (int q = 0; q < 19; ++q) {
            f4 w = wr[q], v = iv[q];
            a += v[0] * w[0] + v[1] * w[1] + v[2] * w[2] + v[3] * w[3];
        }
        hl[r][j] = ftanh(a);
    }
    __syncthreads();

    int rg = tid & 3, cg = tid >> 2;           // rows rg*8.., cols cg*4.. (cg 0..95)
    #pragma unroll 1
    for (int s = 0; s < TMAXN + 1; ++s) {
        // gh = hl @ wh^T + bh   (K=128, N=384)
        {
            f4 bhv = *(const f4*)(&bhs[cg * 4]);
            f4 acc[8];
            #pragma unroll
            for (int i = 0; i < 8; ++i) acc[i] = bhv;
            for (int kq = 0; kq < 32; ++kq) {
                int k = kq * 4;
                f4 w0 = *(const f4*)(wht + (k + 0) * 384 + cg * 4);
                f4 w1 = *(const f4*)(wht + (k + 1) * 384 + cg * 4);
                f4 w2 = *(const f4*)(wht + (k + 2) * 384 + cg * 4);
                f4 w3 = *(const f4*)(wht + (k + 3) * 384 + cg * 4);
                f4 a[8];
                #pragma unroll
                for (int i = 0; i < 8; ++i) a[i] = *(const f4*)(&hl[rg * 8 + i][k]);
                #pragma unroll
                for (int i = 0; i < 8; ++i)
                    acc[i] += a[i][0] * w0 + a[i][1] * w1 + a[i][2] * w2 + a[i][3] * w3;
            }
            #pragma unroll
            for (int i = 0; i < 8; ++i) *(f4*)(&gh[rg * 8 + i][cg * 4]) = acc[i];
        }
        __syncthreads();
        // gates + h update
        for (int idx = tid; idx < 4096; idx += 384) {
            int r = idx >> 7, j = idx & 127;
            float xv = dl[r][s];
            float rr = fsig(xv * wis[j] + bis[j] + gh[r][j]);
            float zz = fsig(xv * wis[j + 128] + bis[j + 128] + gh[r][j + 128]);
            float nn = ftanh(xv * wis[j + 256] + bis[j + 256] + rr * gh[r][j + 256]);
            hl[r][j] = (1.f - zz) * nn + zz * hl[r][j];
        }
        __syncthreads();
        // head
        if (tid < 256) {
            int r = tid >> 3, seg = tid & 7;
            int k0 = seg * 16;
            const f4* hv = (const f4*)(&hl[r][k0]);
            const f4* wa = (const f4*)(hd_w + k0);
            const f4* wb = (const f4*)(hd_w + 128 + k0);
            float p0 = 0.f, p1 = 0.f;
            #pragma unroll
            for (int q = 0; q < 4; ++q) {
                f4 h4 = hv[q], a4 = wa[q], b4 = wb[q];
                p0 += h4[0] * a4[0] + h4[1] * a4[1] + h4[2] * a4[2] + h4[3] * a4[3];
                p1 += h4[0] * b4[0] + h4[1] * b4[1] + h4[2] * b4[2] + h4[3] * b4[3];
            }
            #pragma unroll
            for (int off = 1; off < 8; off <<= 1) {
                p0 += __shfl_xor(p0, off);
                p1 += __shfl_xor(p1, off);
            }
            if (seg == 0) {
                pred[(size_t)(row0 + r) * (TMAXN + 1) + s] = p0 + hd_b[0];
                stopl[(size_t)(row0 + r) * (TMAXN + 1) + s] = p1 + hd_b[1];
            }
        }
    }
}

extern "C" void kernel_launch(void* const* d_in, const int* in_sizes, int n_in,
                              void* d_out, int out_size, void* d_ws, size_t ws_size,
                              hipStream_t stream)
{
    const float* bert       = (const float*)d_in[0];
    const float* times      = (const float*)d_in[1];
    const float* init_noise = (const float*)d_in[2];
    const float* step_noise = (const float*)d_in[3];
    const float* bp_w  = (const float*)d_in[4];
    const float* bp_b  = (const float*)d_in[5];
    const float* ln_g  = (const float*)d_in[6];
    const float* ln_b  = (const float*)d_in[7];
    const float* tp_w1 = (const float*)d_in[8];
    const float* tp_b1 = (const float*)d_in[9];
    const float* tp_w2 = (const float*)d_in[10];
    const float* tp_b2 = (const float*)d_in[11];
    const float* dn_w1 = (const float*)d_in[12];
    const float* dn_b1 = (const float*)d_in[13];
    const float* dn_w2 = (const float*)d_in[14];
    const float* dn_b2 = (const float*)d_in[15];
    const float* dn_w3 = (const float*)d_in[16];
    const float* dn_b3 = (const float*)d_in[17];
    const float* sf_w1 = (const float*)d_in[18];
    const float* sf_b1 = (const float*)d_in[19];
    const float* sf_w2 = (const float*)d_in[20];
    const float* sf_b2 = (const float*)d_in[21];
    const float* sf_w3 = (const float*)d_in[22];
    const float* sf_b3 = (const float*)d_in[23];
    const float* h0_w  = (const float*)d_in[24];
    const float* h0_b  = (const float*)d_in[25];
    const float* gru_wi = (const float*)d_in[26];
    const float* gru_bi = (const float*)d_in[27];
    const float* gru_wh = (const float*)d_in[28];
    const float* gru_bh = (const float*)d_in[29];
    const float* hd_w   = (const float*)d_in[30];
    const float* hd_b   = (const float*)d_in[31];

    float* ws    = (float*)d_ws;
    float* cond  = ws;                          // B*64
    float* te    = cond + (size_t)NB * CONDD;   // 50*64
    float* b1eff = te + SAMPLE_TN * TEMBD;      // 50*256
    float* w1ct  = b1eff + SAMPLE_TN * 256;     // 64*256
    float* w1xt  = w1ct + 64 * 256;             // 10*256
    float* w2t   = w1xt + 10 * 256;             // 256*256
    float* wht   = w2t + 256 * 256;             // 128*384
    float* h0wp  = wht + 128 * 384;             // 128*76
    float* bp_wt = h0wp + 128 * 76;             // 768*64

    // host-side schedule (double, matches numpy)
    double ab[TDIFFN + 1];
    for (int i = 0; i <= TDIFFN; ++i) {
        double xx = (double)i / (double)TDIFFN;
        double v = cos((xx + 0.008) / 1.008 * M_PI * 0.5);
        ab[i] = v * v;
    }
    double ab0 = ab[0];
    for (int i = 0; i <= TDIFFN; ++i) ab[i] /= ab0;
    double betas[TDIFFN], alphas[TDIFFN], abar[TDIFFN];
    double cp = 1.0;
    for (int i = 0; i < TDIFFN; ++i) {
        double b = 1.0 - ab[i + 1] / ab[i];
        if (b > 0.9999) b = 0.9999;
        betas[i] = b; alphas[i] = 1.0 - b;
        cp *= alphas[i]; abar[i] = cp;
    }
    Sched sc;
    for (int s = 0; s < SAMPLE_TN; ++s) {
        int tt = TDIFFN - 1 - 4 * s;
        double abt = abar[tt];
        double abp = (tt > 0) ? abar[tt - 1] : 1.0;
        double beta = betas[tt];
        sc.c1[s] = (float)(sqrt(abp) * beta / (1.0 - abt));
        sc.c2[s] = (float)(sqrt(alphas[tt]) * (1.0 - abp) / (1.0 - abt));
        sc.sv[s] = (float)((tt > 0) ? sqrt((1.0 - abp) / (1.0 - abt) * beta) : 0.0);
        sc.ts[s] = (float)tt;
    }

    float* out    = (float*)d_out;
    float* out_x0 = out;
    float* pred   = out + (size_t)NB * INUMD;
    float* stopl  = pred + (size_t)NB * (TMAXN + 1);

    pack_kernel<<<256, 256, 0, stream>>>(dn_w1, dn_w2, gru_wh, h0_w, bp_w,
                                         w1ct, w1xt, w2t, wht, h0wp, bp_wt);
    bert2_kernel<<<NB / 64, 512, 0, stream>>>(bert, bp_wt, bp_b, ln_g, ln_b, cond);
    te_kernel<<<SAMPLE_TN, 128, 0, stream>>>(tp_w1, tp_b1, tp_w2, tp_b2, te, sc);
    b1eff_kernel<<<SAMPLE_TN, 256, 0, stream>>>(te, dn_w1, dn_b1, b1eff);

    ddpm_all_kernel<<<NB / DR, 256, 0, stream>>>(
        init_noise, cond, step_noise, w1ct, w1xt, b1eff, w2t, dn_b2, dn_w3, dn_b3,
        sc, out_x0);

    gru_all_kernel<<<NB / 32, 384, 0, stream>>>(
        out_x0, cond, times,
        sf_w1, sf_b1, sf_w2, sf_b2, sf_w3, sf_b3,
        h0wp, h0_b, wht, gru_bh, gru_wi, gru_bi, hd_w, hd_b,
        pred, stopl);
}

// Round 4
// 1343.679 us; speedup vs baseline: 7.1065x; 2.9772x over previous
//
#include <hip/hip_runtime.h>
#include <math.h>

typedef float f4 __attribute__((ext_vector_type(4)));
typedef float f32x4 __attribute__((ext_vector_type(4)));
typedef _Float16 f16;
typedef _Float16 f16x8 __attribute__((ext_vector_type(8)));

#define NB 16384
#define BERT_DIM 768
#define CONDD 64
#define INUMD 10
#define RNND 128
#define TDIFFN 200
#define SAMPLE_TN 50
#define TEMBD 64
#define TMAXN 64

struct Sched { float c1[SAMPLE_TN], c2[SAMPLE_TN], sv[SAMPLE_TN], ts[SAMPLE_TN]; };

__device__ __forceinline__ float fsig(float v)  { return __builtin_amdgcn_rcpf(1.f + __expf(-v)); }
__device__ __forceinline__ float ftanh(float v) { return 1.f - 2.f * __builtin_amdgcn_rcpf(1.f + __expf(2.f * v)); }
__device__ __forceinline__ float fsilu(float v) { return v * fsig(v); }

// ---------------- pack: transposed / fp16 weights ----------------
__global__ __launch_bounds__(256) void pack_kernel(
    const float* __restrict__ dn_w1, const float* __restrict__ dn_w2,
    const float* __restrict__ gru_wh, const float* __restrict__ h0_w,
    const float* __restrict__ bp_w,
    float* __restrict__ w1ct, f16* __restrict__ w1x16, f16* __restrict__ w2f16,
    f16* __restrict__ whf16, float* __restrict__ h0wp, float* __restrict__ bp_wt)
{
    int idx = blockIdx.x * 256 + threadIdx.x;   // 0..65535
    if (idx < 16384) { int k = idx >> 8, n = idx & 255; w1ct[idx] = dn_w1[n * 138 + 10 + k]; }
    if (idx < 8192)  { int n = idx >> 5, k = idx & 31; w1x16[idx] = (f16)(k < 10 ? dn_w1[n * 138 + k] : 0.f); }
    if (idx < 65536) { w2f16[idx] = (f16)dn_w2[idx]; }                 // [n=256][k=256]
    if (idx < 49152) { whf16[idx] = (f16)gru_wh[idx]; }                // [n=384][k=128]
    if (idx < 9728)  { int r = idx / 76, c = idx % 76; h0wp[idx] = (c < 74) ? h0_w[r * 74 + c] : 0.f; }
    if (idx < 49152) { int k = idx / 64, n = idx % 64; bp_wt[idx] = bp_w[n * 768 + k]; }
}

// ---------------- bert proj + LN (tiled GEMM, 64 rows/block) ----------------
__global__ __launch_bounds__(512, 1) void bert2_kernel(
    const float* __restrict__ bert, const float* __restrict__ bp_wt,
    const float* __restrict__ bp_b, const float* __restrict__ ln_g,
    const float* __restrict__ ln_b, float* __restrict__ cond)
{
    __shared__ float At[64][68];
    __shared__ float outs[64][68];
    int tid = threadIdx.x;
    int row0 = blockIdx.x * 64;
    int cg = tid & 15, rg = tid >> 4;

    f4 acc[2];
    acc[0] = (f4)0.f; acc[1] = (f4)0.f;
    for (int p = 0; p < 12; ++p) {
        for (int u = tid; u < 64 * 16; u += 512) {
            int row = u >> 4, q = u & 15;
            *(f4*)(&At[row][q * 4]) = *(const f4*)(bert + (size_t)(row0 + row) * BERT_DIM + p * 64 + q * 4);
        }
        __syncthreads();
        for (int kq = 0; kq < 16; ++kq) {
            int k = p * 64 + kq * 4;
            f4 w0 = *(const f4*)(bp_wt + (size_t)(k + 0) * 64 + cg * 4);
            f4 w1 = *(const f4*)(bp_wt + (size_t)(k + 1) * 64 + cg * 4);
            f4 w2 = *(const f4*)(bp_wt + (size_t)(k + 2) * 64 + cg * 4);
            f4 w3 = *(const f4*)(bp_wt + (size_t)(k + 3) * 64 + cg * 4);
            #pragma unroll
            for (int i = 0; i < 2; ++i) {
                f4 a = *(const f4*)(&At[rg * 2 + i][kq * 4]);
                acc[i] += a[0] * w0 + a[1] * w1 + a[2] * w2 + a[3] * w3;
            }
        }
        __syncthreads();
    }
    f4 bb = *(const f4*)(bp_b + cg * 4);
    #pragma unroll
    for (int i = 0; i < 2; ++i) {
        f4 v = acc[i] + bb;
        *(f4*)(&outs[rg * 2 + i][cg * 4]) = v;
    }
    __syncthreads();
    {
        int row = tid >> 3, seg = tid & 7;
        f4 v0 = *(const f4*)(&outs[row][seg * 8]);
        f4 v1 = *(const f4*)(&outs[row][seg * 8 + 4]);
        float s = v0[0]+v0[1]+v0[2]+v0[3]+v1[0]+v1[1]+v1[2]+v1[3];
        float s2 = v0[0]*v0[0]+v0[1]*v0[1]+v0[2]*v0[2]+v0[3]*v0[3]
                 + v1[0]*v1[0]+v1[1]*v1[1]+v1[2]*v1[2]+v1[3]*v1[3];
        #pragma unroll
        for (int off = 1; off < 8; off <<= 1) { s += __shfl_xor(s, off); s2 += __shfl_xor(s2, off); }
        float mu = s * (1.f / 64.f);
        float var = s2 * (1.f / 64.f) - mu * mu;
        float inv = rsqrtf(var + 1e-5f);
        f4 g0 = *(const f4*)(ln_g + seg * 8), g1 = *(const f4*)(ln_g + seg * 8 + 4);
        f4 b0 = *(const f4*)(ln_b + seg * 8), b1 = *(const f4*)(ln_b + seg * 8 + 4);
        f4 o0, o1;
        #pragma unroll
        for (int j = 0; j < 4; ++j) {
            o0[j] = (v0[j] - mu) * inv * g0[j] + b0[j];
            o1[j] = (v1[j] - mu) * inv * g1[j] + b1[j];
        }
        float* dst = cond + (size_t)(row0 + row) * CONDD + seg * 8;
        *(f4*)dst = o0; *(f4*)(dst + 4) = o1;
    }
}

// ---------------- time embedding MLP ----------------
__global__ __launch_bounds__(128) void te_kernel(
    const float* __restrict__ tp_w1, const float* __restrict__ tp_b1,
    const float* __restrict__ tp_w2, const float* __restrict__ tp_b2,
    float* __restrict__ te, Sched sc)
{
    __shared__ float temb[TEMBD];
    __shared__ float h[TEMBD * 2];
    int s = blockIdx.x, t = threadIdx.x;
    if (t < 32) {
        float freq = expf(-logf(10000.f) * (float)t / 31.f);
        float e = sc.ts[s] * freq;
        temb[t] = sinf(e);
        temb[t + 32] = cosf(e);
    }
    __syncthreads();
    float a = tp_b1[t];
    for (int k = 0; k < TEMBD; ++k) a += temb[k] * tp_w1[t * TEMBD + k];
    h[t] = a * (1.f / (1.f + expf(-a)));
    __syncthreads();
    if (t < TEMBD) {
        float a2 = tp_b2[t];
        for (int k = 0; k < 128; ++k) a2 += h[k] * tp_w2[t * 128 + k];
        te[s * TEMBD + t] = a2;
    }
}

// ---------------- b1eff[s][n] = b1[n] + sum_k te[s][k]*w1[n][74+k] ----------------
__global__ __launch_bounds__(256) void b1eff_kernel(
    const float* __restrict__ te, const float* __restrict__ dn_w1,
    const float* __restrict__ dn_b1, float* __restrict__ b1eff)
{
    __shared__ float tes[64];
    int s = blockIdx.x, n = threadIdx.x;
    if (n < 64) tes[n] = te[s * 64 + n];
    __syncthreads();
    float a = dn_b1[n];
    for (int k = 0; k < 64; ++k) a += tes[k] * dn_w1[n * 138 + 74 + k];
    b1eff[s * 256 + n] = a;
}

// ---------------- single-kernel DDPM, fp16 MFMA ----------------
// 512 thr = 8 waves (2 mr x 4 wn), 32 rows/block.
// L1: mfma K=32 (x zero-padded), C = cond1 + b1eff. L2: mfma K=256, B in regs.
// L3 (N=10) + ancestral update: fp32 VALU.
__global__ __launch_bounds__(512, 2) void ddpm_all_kernel(
    const float* __restrict__ x_init, const float* __restrict__ cond,
    const float* __restrict__ noise,
    const float* __restrict__ w1ct, const f16* __restrict__ w1x16,
    const float* __restrict__ b1eff, const f16* __restrict__ w2f16,
    const float* __restrict__ b2g, const float* __restrict__ w3g,
    const float* __restrict__ b3g, Sched sc, float* __restrict__ out_x0)
{
    __shared__ __align__(16) float cond1[32 * 268];
    __shared__ __align__(16) float hbuf[32 * 268];
    __shared__ __align__(16) f16 h1[32 * 256];   // swizzled, row stride 512B
    __shared__ __align__(16) f16 xf16[32 * 32];  // swizzled, row stride 64B
    __shared__ __align__(16) float w3s[10 * 256];
    __shared__ float xbuf[32][12];
    __shared__ float b3s[10];
    int tid = threadIdx.x;
    int row0 = blockIdx.x * 32;
    int lane = tid & 63, wave = tid >> 6;
    int mr = wave >> 2, wn = wave & 3;
    int l15 = lane & 15, l4 = lane >> 4;

    float* condl = hbuf;   // [32][64] staging
    for (int u = tid; u < 32 * 16; u += 512) {
        int r = u >> 4, q = u & 15;
        *(f4*)(condl + r * 64 + q * 4) = *(const f4*)(cond + (size_t)(row0 + r) * 64 + q * 4);
    }
    for (int u = tid; u < 2560; u += 512) w3s[u] = w3g[u];
    if (tid < 10) b3s[tid] = b3g[tid];
    for (int u = tid; u < 1024; u += 512) xf16[u] = (f16)0.f;
    __syncthreads();

    for (int u = tid; u < 320; u += 512) {
        int r = u / 10, k = u % 10;
        float v = x_init[(size_t)(row0 + r) * 10 + k];
        xbuf[r][k] = v;
        *(f16*)((char*)xf16 + ((r * 64 + k * 2) ^ ((r & 7) << 4))) = (f16)v;
    }
    // cond1 = condl @ w1c^T (K=64, fp32)
    {
        int cg = tid & 63, rg = tid >> 6;
        f32x4 cacc[4];
        #pragma unroll
        for (int i = 0; i < 4; ++i) cacc[i] = (f32x4)0.f;
        for (int k = 0; k < 64; ++k) {
            f4 w = *(const f4*)(w1ct + k * 256 + cg * 4);
            #pragma unroll
            for (int i = 0; i < 4; ++i) cacc[i] += condl[(rg * 4 + i) * 64 + k] * w;
        }
        #pragma unroll
        for (int i = 0; i < 4; ++i) *(f32x4*)(cond1 + (rg * 4 + i) * 268 + cg * 4) = cacc[i];
    }
    // preload B fragments (registers, once)
    f16x8 B2[4][8], B1[4];
    #pragma unroll
    for (int t = 0; t < 4; ++t) {
        int col = wn * 64 + t * 16 + l15;
        B1[t] = *(const f16x8*)(w1x16 + col * 32 + l4 * 8);
        #pragma unroll
        for (int kb = 0; kb < 8; ++kb)
            B2[t][kb] = *(const f16x8*)(w2f16 + col * 256 + kb * 32 + l4 * 8);
    }
    __syncthreads();

    int arow = mr * 16 + l15;
    int aswz = (arow & 7) << 4;

    #pragma unroll 1
    for (int s = 0; s < SAMPLE_TN; ++s) {
        // ---- L1 MFMA: h1 = silu(x @ w1x^T + cond1 + b1eff) ----
        {
            f16x8 ax = *(const f16x8*)((const char*)xf16 + ((arow * 64 + l4 * 16) ^ aswz));
            #pragma unroll
            for (int t = 0; t < 4; ++t) {
                int col = wn * 64 + t * 16 + l15;
                float be = b1eff[s * 256 + col];
                f32x4 ci;
                #pragma unroll
                for (int r = 0; r < 4; ++r) ci[r] = cond1[(mr * 16 + l4 * 4 + r) * 268 + col] + be;
                f32x4 hv = __builtin_amdgcn_mfma_f32_16x16x32_f16(ax, B1[t], ci, 0, 0, 0);
                #pragma unroll
                for (int r = 0; r < 4; ++r) {
                    int row = mr * 16 + l4 * 4 + r;
                    *(f16*)((char*)h1 + ((row * 512 + col * 2) ^ ((row & 7) << 4))) = (f16)fsilu(hv[r]);
                }
            }
        }
        __syncthreads();
        // ---- L2 MFMA: h2 = silu(h1 @ w2^T + b2) ----
        {
            f32x4 acc[4];
            #pragma unroll
            for (int t = 0; t < 4; ++t) acc[t] = (f32x4)0.f;
            #pragma unroll
            for (int kb = 0; kb < 8; ++kb) {
                f16x8 a = *(const f16x8*)((const char*)h1 + ((arow * 512 + kb * 64 + l4 * 16) ^ aswz));
                #pragma unroll
                for (int t = 0; t < 4; ++t)
                    acc[t] = __builtin_amdgcn_mfma_f32_16x16x32_f16(a, B2[t][kb], acc[t], 0, 0, 0);
            }
            #pragma unroll
            for (int t = 0; t < 4; ++t) {
                int col = wn * 64 + t * 16 + l15;
                float b2v = b2g[col];
                #pragma unroll
                for (int r = 0; r < 4; ++r) {
                    int row = mr * 16 + l4 * 4 + r;
                    hbuf[row * 268 + col] = fsilu(acc[t][r] + b2v);
                }
            }
        }
        __syncthreads();
        // ---- L3 (N=10) + ancestral update ----
        if (tid < 256) {
            int r3 = tid >> 3, seg = tid & 7;
            float p[10];
            #pragma unroll
            for (int o = 0; o < 10; ++o) p[o] = 0.f;
            #pragma unroll
            for (int kq = 0; kq < 8; ++kq) {
                int k = seg * 4 + kq * 32;
                f4 a = *(const f4*)(hbuf + r3 * 268 + k);
                #pragma unroll
                for (int o = 0; o < 10; ++o) {
                    f4 w = *(const f4*)(w3s + o * 256 + k);
                    p[o] += a[0] * w[0] + a[1] * w[1] + a[2] * w[2] + a[3] * w[3];
                }
            }
            #pragma unroll
            for (int o = 0; o < 10; ++o) {
                p[o] += __shfl_xor(p[o], 1);
                p[o] += __shfl_xor(p[o], 2);
                p[o] += __shfl_xor(p[o], 4);
            }
            if (seg == 0) {
                float c1 = sc.c1[s], c2 = sc.c2[s], sv = sc.sv[s];
                const float* nz = noise + ((size_t)s * NB + row0 + r3) * 10;
                #pragma unroll
                for (int o = 0; o < 10; ++o) {
                    float xn = c1 * (p[o] + b3s[o]) + c2 * xbuf[r3][o] + sv * nz[o];
                    xbuf[r3][o] = xn;
                    *(f16*)((char*)xf16 + ((r3 * 64 + o * 2) ^ ((r3 & 7) << 4))) = (f16)xn;
                }
            }
        }
        __syncthreads();
    }
    for (int u = tid; u < 320; u += 512) {
        int r = u / 10, k = u % 10;
        out_x0[(size_t)(row0 + r) * 10 + k] = xbuf[r][k];
    }
}

// ---------------- single-kernel GRU, fp16 MFMA, gates in registers ----------------
// 512 thr = 8 waves (2 mr x 4 wn), 32 rows/block. Wave wn owns h-cols [wn*32, wn*32+32)
// for ALL 3 gates -> r,z,n local to lane. h state in registers; hl double-buffered fp16 LDS.
__global__ __launch_bounds__(512, 2) void gru_all_kernel(
    const float* __restrict__ x0, const float* __restrict__ cond,
    const float* __restrict__ times,
    const float* __restrict__ sf_w1, const float* __restrict__ sf_b1,
    const float* __restrict__ sf_w2, const float* __restrict__ sf_b2,
    const float* __restrict__ sf_w3, const float* __restrict__ sf_b3,
    const float* __restrict__ h0wp, const float* __restrict__ h0_b,
    const f16* __restrict__ whf16, const float* __restrict__ gru_bh,
    const float* __restrict__ gru_wi, const float* __restrict__ gru_bi,
    const float* __restrict__ hd_w, const float* __restrict__ hd_b,
    float* __restrict__ pred, float* __restrict__ stopl)
{
    __shared__ __align__(16) f16 hl[2][32 * 128];   // swizzled, row stride 256B
    __shared__ float dl[32 * 66];
    __shared__ __align__(16) float scratch[3840];
    __shared__ float wis[384], bis[384], bhs[384];
    __shared__ float headp[2][32 * 8];
    int tid = threadIdx.x;
    int row0 = blockIdx.x * 32;
    int lane = tid & 63, wave = tid >> 6;
    int mr = wave >> 2, wn = wave & 3;
    int l15 = lane & 15, l4 = lane >> 4;

    if (tid < 384) { wis[tid] = gru_wi[tid]; bis[tid] = gru_bi[tid]; bhs[tid] = gru_bh[tid]; }
    // times -> deltas
    float* tb = scratch;   // [32][64]
    for (int u = tid; u < 2048; u += 512) {
        int r = u >> 6, k = u & 63;
        tb[u] = times[(size_t)(row0 + r) * TMAXN + k];
    }
    __syncthreads();
    float dtmp[5]; int c = 0;
    for (int idx = tid; idx < 2080; idx += 512) {
        int r = idx / 65, i = idx % 65;
        float v;
        if (i == 0) v = 0.f;
        else if (i == 1) v = tb[r * 64];
        else v = tb[r * 64 + i - 1] - tb[r * 64 + i - 2];
        dtmp[c++] = v;
    }
    __syncthreads();
    c = 0;
    for (int idx = tid; idx < 2080; idx += 512) {
        int r = idx / 65, i = idx % 65;
        dl[r * 66 + i] = dtmp[c++];
    }
    // seq MLP + h0 (scratch reuse)
    float* in2 = scratch;            // [32][76]
    float* sbuf = scratch + 32 * 76; // [32][44]
    for (int idx = tid; idx < 2048; idx += 512) {
        int r = idx >> 6, k = idx & 63;
        in2[r * 76 + k] = cond[(size_t)(row0 + r) * CONDD + k];
    }
    for (int idx = tid; idx < 320; idx += 512) {
        int r = idx / 10, k = idx % 10;
        in2[r * 76 + 64 + k] = x0[(size_t)(row0 + r) * 10 + k];
    }
    if (tid < 64) { int r = tid >> 1; in2[r * 76 + 74 + (tid & 1)] = 0.f; }
    __syncthreads();
    for (int idx = tid; idx < 640; idx += 512) {
        int r = idx / 20, j = idx % 20;
        float a = sf_b1[j];
        for (int k = 0; k < 10; ++k) a += in2[r * 76 + 64 + k] * sf_w1[j * 10 + k];
        sbuf[r * 44 + j] = fmaxf(a, 0.f);
    }
    __syncthreads();
    for (int idx = tid; idx < 640; idx += 512) {
        int r = idx / 20, j = idx % 20;
        float a = sf_b2[j];
        for (int k = 0; k < 20; ++k) a += sbuf[r * 44 + k] * sf_w2[j * 20 + k];
        sbuf[r * 44 + 22 + j] = fmaxf(a, 0.f);
    }
    __syncthreads();
    for (int idx = tid; idx < 320; idx += 512) {
        int r = idx / 10, j = idx % 10;
        float a = sf_b3[j];
        for (int k = 0; k < 20; ++k) a += sbuf[r * 44 + 22 + k] * sf_w3[j * 20 + k];
        in2[r * 76 + 64 + j] = a;
    }
    __syncthreads();
    for (int idx = tid; idx < 4096; idx += 512) {
        int r = idx >> 7, j = idx & 127;
        float a = h0_b[j];
        const f4* wr = (const f4*)(h0wp + j * 76);
        const f4* iv = (const f4*)(in2 + r * 76);
        #pragma unroll
        for (int q = 0; q < 19; ++q) {
            f4 w = wr[q], v = iv[q];
            a += v[0] * w[0] + v[1] * w[1] + v[2] * w[2] + v[3] * w[3];
        }
        *(f16*)((char*)hl[0] + ((r * 256 + j * 2) ^ ((r & 7) << 4))) = (f16)ftanh(a);
    }
    __syncthreads();

    // per-lane state: B frags, gate params, h registers
    f16x8 BW[3][2][4];
    float wi_[3][2], bi_[3][2], bh_[3][2], hw0[2], hw1[2];
    #pragma unroll
    for (int g = 0; g < 3; ++g)
        #pragma unroll
        for (int ct = 0; ct < 2; ++ct) {
            int jc = wn * 32 + ct * 16 + l15;
            int col = g * 128 + jc;
            #pragma unroll
            for (int kb = 0; kb < 4; ++kb)
                BW[g][ct][kb] = *(const f16x8*)(whf16 + col * 128 + kb * 32 + l4 * 8);
            wi_[g][ct] = wis[col]; bi_[g][ct] = bis[col]; bh_[g][ct] = bhs[col];
            if (g == 0) { hw0[ct] = hd_w[jc]; hw1[ct] = hd_w[128 + jc]; }
        }
    float hreg[2][4];
    #pragma unroll
    for (int ct = 0; ct < 2; ++ct)
        #pragma unroll
        for (int r = 0; r < 4; ++r) {
            int row = mr * 16 + l4 * 4 + r;
            int jc = wn * 32 + ct * 16 + l15;
            hreg[ct][r] = (float)(*(const f16*)((const char*)hl[0] + ((row * 256 + jc * 2) ^ ((row & 7) << 4))));
        }
    int arow = mr * 16 + l15;
    int aswz = (arow & 7) << 4;

    #pragma unroll 1
    for (int s = 0; s < TMAXN + 1; ++s) {
        const f16* cur = hl[s & 1];
        f16* nxt = hl[(s + 1) & 1];
        f16x8 A[4];
        #pragma unroll
        for (int kb = 0; kb < 4; ++kb)
            A[kb] = *(const f16x8*)((const char*)cur + ((arow * 256 + kb * 64 + l4 * 16) ^ aswz));
        f32x4 acc[3][2];
        #pragma unroll
        for (int g = 0; g < 3; ++g)
            #pragma unroll
            for (int ct = 0; ct < 2; ++ct) {
                f32x4 ci; ci[0] = ci[1] = ci[2] = ci[3] = bh_[g][ct];
                acc[g][ct] = ci;
            }
        #pragma unroll
        for (int kb = 0; kb < 4; ++kb)
            #pragma unroll
            for (int g = 0; g < 3; ++g)
                #pragma unroll
                for (int ct = 0; ct < 2; ++ct)
                    acc[g][ct] = __builtin_amdgcn_mfma_f32_16x16x32_f16(A[kb], BW[g][ct][kb], acc[g][ct], 0, 0, 0);
        float p0[4], p1[4];
        #pragma unroll
        for (int r = 0; r < 4; ++r) {
            int row = mr * 16 + l4 * 4 + r;
            float xv = dl[row * 66 + s];
            p0[r] = 0.f; p1[r] = 0.f;
            #pragma unroll
            for (int ct = 0; ct < 2; ++ct) {
                float rr = fsig(xv * wi_[0][ct] + bi_[0][ct] + acc[0][ct][r]);
                float zz = fsig(xv * wi_[1][ct] + bi_[1][ct] + acc[1][ct][r]);
                float nn = ftanh(xv * wi_[2][ct] + bi_[2][ct] + rr * acc[2][ct][r]);
                float hn = (1.f - zz) * nn + zz * hreg[ct][r];
                hreg[ct][r] = hn;
                int jc = wn * 32 + ct * 16 + l15;
                *(f16*)((char*)nxt + ((row * 256 + jc * 2) ^ ((row & 7) << 4))) = (f16)hn;
                p0[r] += hn * hw0[ct];
                p1[r] += hn * hw1[ct];
            }
        }
        #pragma unroll
        for (int r = 0; r < 4; ++r) {
            #pragma unroll
            for (int off = 1; off < 16; off <<= 1) {
                p0[r] += __shfl_xor(p0[r], off);
                p1[r] += __shfl_xor(p1[r], off);
            }
        }
        if (l15 == 0) {
            #pragma unroll
            for (int r = 0; r < 4; ++r) {
                int row = mr * 16 + l4 * 4 + r;
                headp[s & 1][row * 8 + wn] = p0[r];
                headp[s & 1][row * 8 + 4 + wn] = p1[r];
            }
        }
        __syncthreads();
        if (tid < 64) {
            int r = tid >> 1, o = tid & 1;
            const float* hp = &headp[s & 1][r * 8 + o * 4];
            float v = hd_b[o] + hp[0] + hp[1] + hp[2] + hp[3];
            float* dst = o ? stopl : pred;
            dst[(size_t)(row0 + r) * (TMAXN + 1) + s] = v;
        }
    }
}

extern "C" void kernel_launch(void* const* d_in, const int* in_sizes, int n_in,
                              void* d_out, int out_size, void* d_ws, size_t ws_size,
                              hipStream_t stream)
{
    const float* bert       = (const float*)d_in[0];
    const float* times      = (const float*)d_in[1];
    const float* init_noise = (const float*)d_in[2];
    const float* step_noise = (const float*)d_in[3];
    const float* bp_w  = (const float*)d_in[4];
    const float* bp_b  = (const float*)d_in[5];
    const float* ln_g  = (const float*)d_in[6];
    const float* ln_b  = (const float*)d_in[7];
    const float* tp_w1 = (const float*)d_in[8];
    const float* tp_b1 = (const float*)d_in[9];
    const float* tp_w2 = (const float*)d_in[10];
    const float* tp_b2 = (const float*)d_in[11];
    const float* dn_w1 = (const float*)d_in[12];
    const float* dn_b1 = (const float*)d_in[13];
    const float* dn_w2 = (const float*)d_in[14];
    const float* dn_b2 = (const float*)d_in[15];
    const float* dn_w3 = (const float*)d_in[16];
    const float* dn_b3 = (const float*)d_in[17];
    const float* sf_w1 = (const float*)d_in[18];
    const float* sf_b1 = (const float*)d_in[19];
    const float* sf_w2 = (const float*)d_in[20];
    const float* sf_b2 = (const float*)d_in[21];
    const float* sf_w3 = (const float*)d_in[22];
    const float* sf_b3 = (const float*)d_in[23];
    const float* h0_w  = (const float*)d_in[24];
    const float* h0_b  = (const float*)d_in[25];
    const float* gru_wi = (const float*)d_in[26];
    const float* gru_bi = (const float*)d_in[27];
    const float* gru_wh = (const float*)d_in[28];
    const float* gru_bh = (const float*)d_in[29];
    const float* hd_w   = (const float*)d_in[30];
    const float* hd_b   = (const float*)d_in[31];

    float* ws    = (float*)d_ws;
    float* cond  = ws;                          // B*64
    float* te    = cond + (size_t)NB * CONDD;   // 50*64
    float* b1eff = te + SAMPLE_TN * TEMBD;      // 50*256
    float* w1ct  = b1eff + SAMPLE_TN * 256;     // 64*256 (fp32, k-major)
    float* h0wp  = w1ct + 64 * 256;             // 128*76
    float* bp_wt = h0wp + 128 * 76;             // 768*64
    f16*   w1x16 = (f16*)(bp_wt + 768 * 64);    // 256*32 f16
    f16*   w2f16 = w1x16 + 256 * 32;            // 256*256 f16
    f16*   whf16 = w2f16 + 256 * 256;           // 384*128 f16

    // host-side schedule (double, matches numpy)
    double ab[TDIFFN + 1];
    for (int i = 0; i <= TDIFFN; ++i) {
        double xx = (double)i / (double)TDIFFN;
        double v = cos((xx + 0.008) / 1.008 * M_PI * 0.5);
        ab[i] = v * v;
    }
    double ab0 = ab[0];
    for (int i = 0; i <= TDIFFN; ++i) ab[i] /= ab0;
    double betas[TDIFFN], alphas[TDIFFN], abar[TDIFFN];
    double cp = 1.0;
    for (int i = 0; i < TDIFFN; ++i) {
        double b = 1.0 - ab[i + 1] / ab[i];
        if (b > 0.9999) b = 0.9999;
        betas[i] = b; alphas[i] = 1.0 - b;
        cp *= alphas[i]; abar[i] = cp;
    }
    Sched sc;
    for (int s = 0; s < SAMPLE_TN; ++s) {
        int tt = TDIFFN - 1 - 4 * s;
        double abt = abar[tt];
        double abp = (tt > 0) ? abar[tt - 1] : 1.0;
        double beta = betas[tt];
        sc.c1[s] = (float)(sqrt(abp) * beta / (1.0 - abt));
        sc.c2[s] = (float)(sqrt(alphas[tt]) * (1.0 - abp) / (1.0 - abt));
        sc.sv[s] = (float)((tt > 0) ? sqrt((1.0 - abp) / (1.0 - abt) * beta) : 0.0);
        sc.ts[s] = (float)tt;
    }

    float* out    = (float*)d_out;
    float* out_x0 = out;
    float* pred   = out + (size_t)NB * INUMD;
    float* stopl  = pred + (size_t)NB * (TMAXN + 1);

    pack_kernel<<<256, 256, 0, stream>>>(dn_w1, dn_w2, gru_wh, h0_w, bp_w,
                                         w1ct, w1x16, w2f16, whf16, h0wp, bp_wt);
    bert2_kernel<<<NB / 64, 512, 0, stream>>>(bert, bp_wt, bp_b, ln_g, ln_b, cond);
    te_kernel<<<SAMPLE_TN, 128, 0, stream>>>(tp_w1, tp_b1, tp_w2, tp_b2, te, sc);
    b1eff_kernel<<<SAMPLE_TN, 256, 0, stream>>>(te, dn_w1, dn_b1, b1eff);

    ddpm_all_kernel<<<NB / 32, 512, 0, stream>>>(
        init_noise, cond, step_noise, w1ct, w1x16, b1eff, w2f16, dn_b2, dn_w3, dn_b3,
        sc, out_x0);

    gru_all_kernel<<<NB / 32, 512, 0, stream>>>(
        out_x0, cond, times,
        sf_w1, sf_b1, sf_w2, sf_b2, sf_w3, sf_b3,
        h0wp, h0_b, whf16, gru_bh, gru_wi, gru_bi, hd_w, hd_b,
        pred, stopl);
}

// Round 5
// 660.907 us; speedup vs baseline: 14.4481x; 2.0331x over previous
//
#include <hip/hip_runtime.h>
#include <math.h>

typedef float f4 __attribute__((ext_vector_type(4)));
typedef float f32x4 __attribute__((ext_vector_type(4)));
typedef _Float16 f16;
typedef _Float16 f16x8 __attribute__((ext_vector_type(8)));

#define NB 16384
#define BERT_DIM 768
#define CONDD 64
#define INUMD 10
#define RNND 128
#define TDIFFN 200
#define SAMPLE_TN 50
#define TEMBD 64
#define TMAXN 64

struct Sched { float c1[SAMPLE_TN], c2[SAMPLE_TN], sv[SAMPLE_TN], ts[SAMPLE_TN]; };

__device__ __forceinline__ float fsig(float v)  { return __builtin_amdgcn_rcpf(1.f + __expf(-v)); }
__device__ __forceinline__ float ftanh(float v) { return 1.f - 2.f * __builtin_amdgcn_rcpf(1.f + __expf(2.f * v)); }
__device__ __forceinline__ float fsilu(float v) { return v * fsig(v); }

// ---------------- pack: transposed / fp16 weights ----------------
__global__ __launch_bounds__(256) void pack_kernel(
    const float* __restrict__ dn_w1, const float* __restrict__ dn_w2,
    const float* __restrict__ dn_w3, const float* __restrict__ gru_wh,
    const float* __restrict__ h0_w, const float* __restrict__ bp_w,
    float* __restrict__ w1ct, f16* __restrict__ w1x16, f16* __restrict__ w2f16,
    f16* __restrict__ whf16, float* __restrict__ h0wp, float* __restrict__ bp_wt,
    f16* __restrict__ w3f16)
{
    int idx = blockIdx.x * 256 + threadIdx.x;   // 0..65535
    if (idx < 16384) { int k = idx >> 8, n = idx & 255; w1ct[idx] = dn_w1[n * 138 + 10 + k]; }
    if (idx < 8192)  { int n = idx >> 5, k = idx & 31; w1x16[idx] = (f16)(k < 10 ? dn_w1[n * 138 + k] : 0.f); }
    if (idx < 65536) { w2f16[idx] = (f16)dn_w2[idx]; }                 // [n=256][k=256]
    if (idx < 49152) { whf16[idx] = (f16)gru_wh[idx]; }                // [n=384][k=128]
    if (idx < 9728)  { int r = idx / 76, c = idx % 76; h0wp[idx] = (c < 74) ? h0_w[r * 74 + c] : 0.f; }
    if (idx < 49152) { int k = idx / 64, n = idx % 64; bp_wt[idx] = bp_w[n * 768 + k]; }
    if (idx < 4096)  { int n = idx >> 8, k = idx & 255; w3f16[idx] = (f16)(n < 10 ? dn_w3[n * 256 + k] : 0.f); }
}

// ---------------- bert proj + LN (tiled GEMM, 64 rows/block) ----------------
__global__ __launch_bounds__(512, 1) void bert2_kernel(
    const float* __restrict__ bert, const float* __restrict__ bp_wt,
    const float* __restrict__ bp_b, const float* __restrict__ ln_g,
    const float* __restrict__ ln_b, float* __restrict__ cond)
{
    __shared__ float At[64][68];
    __shared__ float outs[64][68];
    int tid = threadIdx.x;
    int row0 = blockIdx.x * 64;
    int cg = tid & 15, rg = tid >> 4;

    f4 acc[2];
    acc[0] = (f4)0.f; acc[1] = (f4)0.f;
    for (int p = 0; p < 12; ++p) {
        for (int u = tid; u < 64 * 16; u += 512) {
            int row = u >> 4, q = u & 15;
            *(f4*)(&At[row][q * 4]) = *(const f4*)(bert + (size_t)(row0 + row) * BERT_DIM + p * 64 + q * 4);
        }
        __syncthreads();
        for (int kq = 0; kq < 16; ++kq) {
            int k = p * 64 + kq * 4;
            f4 w0 = *(const f4*)(bp_wt + (size_t)(k + 0) * 64 + cg * 4);
            f4 w1 = *(const f4*)(bp_wt + (size_t)(k + 1) * 64 + cg * 4);
            f4 w2 = *(const f4*)(bp_wt + (size_t)(k + 2) * 64 + cg * 4);
            f4 w3 = *(const f4*)(bp_wt + (size_t)(k + 3) * 64 + cg * 4);
            #pragma unroll
            for (int i = 0; i < 2; ++i) {
                f4 a = *(const f4*)(&At[rg * 2 + i][kq * 4]);
                acc[i] += a[0] * w0 + a[1] * w1 + a[2] * w2 + a[3] * w3;
            }
        }
        __syncthreads();
    }
    f4 bb = *(const f4*)(bp_b + cg * 4);
    #pragma unroll
    for (int i = 0; i < 2; ++i) {
        f4 v = acc[i] + bb;
        *(f4*)(&outs[rg * 2 + i][cg * 4]) = v;
    }
    __syncthreads();
    {
        int row = tid >> 3, seg = tid & 7;
        f4 v0 = *(const f4*)(&outs[row][seg * 8]);
        f4 v1 = *(const f4*)(&outs[row][seg * 8 + 4]);
        float s = v0[0]+v0[1]+v0[2]+v0[3]+v1[0]+v1[1]+v1[2]+v1[3];
        float s2 = v0[0]*v0[0]+v0[1]*v0[1]+v0[2]*v0[2]+v0[3]*v0[3]
                 + v1[0]*v1[0]+v1[1]*v1[1]+v1[2]*v1[2]+v1[3]*v1[3];
        #pragma unroll
        for (int off = 1; off < 8; off <<= 1) { s += __shfl_xor(s, off); s2 += __shfl_xor(s2, off); }
        float mu = s * (1.f / 64.f);
        float var = s2 * (1.f / 64.f) - mu * mu;
        float inv = rsqrtf(var + 1e-5f);
        f4 g0 = *(const f4*)(ln_g + seg * 8), g1 = *(const f4*)(ln_g + seg * 8 + 4);
        f4 b0 = *(const f4*)(ln_b + seg * 8), b1 = *(const f4*)(ln_b + seg * 8 + 4);
        f4 o0, o1;
        #pragma unroll
        for (int j = 0; j < 4; ++j) {
            o0[j] = (v0[j] - mu) * inv * g0[j] + b0[j];
            o1[j] = (v1[j] - mu) * inv * g1[j] + b1[j];
        }
        float* dst = cond + (size_t)(row0 + row) * CONDD + seg * 8;
        *(f4*)dst = o0; *(f4*)(dst + 4) = o1;
    }
}

// ---------------- time embedding MLP ----------------
__global__ __launch_bounds__(128) void te_kernel(
    const float* __restrict__ tp_w1, const float* __restrict__ tp_b1,
    const float* __restrict__ tp_w2, const float* __restrict__ tp_b2,
    float* __restrict__ te, Sched sc)
{
    __shared__ float temb[TEMBD];
    __shared__ float h[TEMBD * 2];
    int s = blockIdx.x, t = threadIdx.x;
    if (t < 32) {
        float freq = expf(-logf(10000.f) * (float)t / 31.f);
        float e = sc.ts[s] * freq;
        temb[t] = sinf(e);
        temb[t + 32] = cosf(e);
    }
    __syncthreads();
    float a = tp_b1[t];
    for (int k = 0; k < TEMBD; ++k) a += temb[k] * tp_w1[t * TEMBD + k];
    h[t] = a * (1.f / (1.f + expf(-a)));
    __syncthreads();
    if (t < TEMBD) {
        float a2 = tp_b2[t];
        for (int k = 0; k < 128; ++k) a2 += h[k] * tp_w2[t * 128 + k];
        te[s * TEMBD + t] = a2;
    }
}

// ---------------- b1eff[s][n] = b1[n] + sum_k te[s][k]*w1[n][74+k] ----------------
__global__ __launch_bounds__(256) void b1eff_kernel(
    const float* __restrict__ te, const float* __restrict__ dn_w1,
    const float* __restrict__ dn_b1, float* __restrict__ b1eff)
{
    __shared__ float tes[64];
    int s = blockIdx.x, n = threadIdx.x;
    if (n < 64) tes[n] = te[s * 64 + n];
    __syncthreads();
    float a = dn_b1[n];
    for (int k = 0; k < 64; ++k) a += tes[k] * dn_w1[n * 138 + 74 + k];
    b1eff[s * 256 + n] = a;
}

// ---------------- single-kernel DDPM v2: 16 rows/block, 4 waves, 2 barriers/step ----------------
// wave wn owns output cols [wn*64, wn*64+64). cond1 in registers (MFMA-C layout).
// L1: mfma K=32 (x padded), C = cond1+b1eff. L2: mfma K=256, B2 in regs.
// L3: mfma vs zero-padded w3 (N=16); x-update in-lane; per-wave fp16 x buffer, no 3rd barrier.
__global__ __launch_bounds__(256, 2) void ddpm_all_kernel(
    const float* __restrict__ x_init, const float* __restrict__ cond,
    const float* __restrict__ noise,
    const float* __restrict__ w1ct, const f16* __restrict__ w1x16,
    const float* __restrict__ b1eff, const f16* __restrict__ w2f16,
    const float* __restrict__ b2g, const f16* __restrict__ w3f16,
    const float* __restrict__ b3g, Sched sc, float* __restrict__ out_x0)
{
    __shared__ __align__(16) f16 h1[16 * 256];      // swizzled, row stride 512B
    __shared__ __align__(16) f16 h2[16 * 256];      // swizzled, row stride 512B
    __shared__ __align__(16) f16 xw[4][16 * 32];    // per-wave x, linear, row stride 64B
    int tid = threadIdx.x;
    int row0 = blockIdx.x * 16;
    int lane = tid & 63, wn = tid >> 6;
    int l15 = lane & 15, l4 = lane >> 4;

    // stage cond fp32 into h1-scratch; zero own-wave x buffer
    float* condl = (float*)h1;   // [16][64]
    for (int u = tid; u < 16 * 16; u += 256) {
        int r = u >> 4, q = u & 15;
        *(f4*)(condl + r * 64 + q * 4) = *(const f4*)(cond + (size_t)(row0 + r) * 64 + q * 4);
    }
    *(f4*)((float*)xw[wn] + lane * 4) = (f4)0.f;     // 64 lanes x 16B = 1KB
    __syncthreads();

    // cond1 in regs: c1r[t][r] = sum_k cond[row=l4*4+r][k] * w1c[col=wn*64+t*16+l15][k]
    f32x4 c1r[4];
    #pragma unroll
    for (int t = 0; t < 4; ++t) c1r[t] = (f32x4)0.f;
    for (int kq = 0; kq < 16; ++kq) {
        f4 cr[4];
        #pragma unroll
        for (int r = 0; r < 4; ++r) cr[r] = *(const f4*)(condl + (l4 * 4 + r) * 64 + kq * 4);
        #pragma unroll
        for (int t = 0; t < 4; ++t) {
            int col = wn * 64 + t * 16 + l15;
            #pragma unroll
            for (int j = 0; j < 4; ++j) {
                float w = w1ct[(kq * 4 + j) * 256 + col];
                #pragma unroll
                for (int r = 0; r < 4; ++r) c1r[t][r] += cr[r][j] * w;
            }
        }
    }
    __syncthreads();   // condl scratch done; h1 free for reuse

    // preload weights into registers
    f16x8 B2[4][8], B1[4], W3[8];
    float b2v[4];
    #pragma unroll
    for (int t = 0; t < 4; ++t) {
        int col = wn * 64 + t * 16 + l15;
        B1[t] = *(const f16x8*)(w1x16 + col * 32 + l4 * 8);
        #pragma unroll
        for (int kb = 0; kb < 8; ++kb)
            B2[t][kb] = *(const f16x8*)(w2f16 + col * 256 + kb * 32 + l4 * 8);
        b2v[t] = b2g[col];
    }
    #pragma unroll
    for (int kb = 0; kb < 8; ++kb)
        W3[kb] = *(const f16x8*)(w3f16 + l15 * 256 + kb * 32 + l4 * 8);
    float b3v = (l15 < 10) ? b3g[l15] : 0.f;

    // x state in regs (rows l4*4+r, k=l15) + own-wave fp16 copy
    float xo[4] = {0.f, 0.f, 0.f, 0.f};
    if (l15 < 10) {
        #pragma unroll
        for (int r = 0; r < 4; ++r) {
            xo[r] = x_init[(size_t)(row0 + l4 * 4 + r) * INUMD + l15];
            xw[wn][(l4 * 4 + r) * 32 + l15] = (f16)xo[r];
        }
    }
    float be[4];
    #pragma unroll
    for (int t = 0; t < 4; ++t) be[t] = b1eff[wn * 64 + t * 16 + l15];

    int axoff = l15 * 64 + l4 * 16;   // bytes in xw[wn]
    #pragma unroll 1
    for (int s = 0; s < SAMPLE_TN; ++s) {
        // ---- L1: h1 = silu(x @ w1x^T + cond1 + b1eff[s]) ----
        f16x8 ax = *(const f16x8*)((const char*)xw[wn] + axoff);
        #pragma unroll
        for (int t = 0; t < 4; ++t) {
            f32x4 ci;
            #pragma unroll
            for (int r = 0; r < 4; ++r) ci[r] = c1r[t][r] + be[t];
            f32x4 a1 = __builtin_amdgcn_mfma_f32_16x16x32_f16(ax, B1[t], ci, 0, 0, 0);
            int col = wn * 64 + t * 16 + l15;
            #pragma unroll
            for (int r = 0; r < 4; ++r) {
                int row = l4 * 4 + r;
                *(f16*)((char*)h1 + ((row * 512 + col * 2) ^ ((row & 7) << 4))) = (f16)fsilu(a1[r]);
            }
        }
        // prefetch noise (used in L3) and next-step b1eff
        float nz[4] = {0.f, 0.f, 0.f, 0.f};
        if (l15 < 10) {
            #pragma unroll
            for (int r = 0; r < 4; ++r)
                nz[r] = noise[((size_t)s * NB + row0 + l4 * 4 + r) * INUMD + l15];
        }
        if (s + 1 < SAMPLE_TN) {
            #pragma unroll
            for (int t = 0; t < 4; ++t) be[t] = b1eff[(s + 1) * 256 + wn * 64 + t * 16 + l15];
        }
        __syncthreads();
        // ---- L2: h2 = silu(h1 @ w2^T + b2) ----
        {
            f32x4 a2[4];
            #pragma unroll
            for (int t = 0; t < 4; ++t) a2[t] = (f32x4)0.f;
            #pragma unroll
            for (int kb = 0; kb < 8; ++kb) {
                f16x8 A = *(const f16x8*)((const char*)h1 +
                          (l15 * 512 + ((kb * 64 + l4 * 16) ^ ((l15 & 7) << 4))));
                #pragma unroll
                for (int t = 0; t < 4; ++t)
                    a2[t] = __builtin_amdgcn_mfma_f32_16x16x32_f16(A, B2[t][kb], a2[t], 0, 0, 0);
            }
            #pragma unroll
            for (int t = 0; t < 4; ++t) {
                int col = wn * 64 + t * 16 + l15;
                #pragma unroll
                for (int r = 0; r < 4; ++r) {
                    int row = l4 * 4 + r;
                    *(f16*)((char*)h2 + ((row * 512 + col * 2) ^ ((row & 7) << 4))) = (f16)fsilu(a2[t][r] + b2v[t]);
                }
            }
        }
        __syncthreads();
        // ---- L3: p = h2 @ w3^T (N=16 padded), then ancestral update in-lane ----
        {
            f32x4 pa = (f32x4)0.f, pb = (f32x4)0.f;
            #pragma unroll
            for (int kb = 0; kb < 8; kb += 2) {
                f16x8 A0 = *(const f16x8*)((const char*)h2 +
                           (l15 * 512 + (((kb + 0) * 64 + l4 * 16) ^ ((l15 & 7) << 4))));
                f16x8 A1 = *(const f16x8*)((const char*)h2 +
                           (l15 * 512 + (((kb + 1) * 64 + l4 * 16) ^ ((l15 & 7) << 4))));
                pa = __builtin_amdgcn_mfma_f32_16x16x32_f16(A0, W3[kb + 0], pa, 0, 0, 0);
                pb = __builtin_amdgcn_mfma_f32_16x16x32_f16(A1, W3[kb + 1], pb, 0, 0, 0);
            }
            if (l15 < 10) {
                float c1s = sc.c1[s], c2s = sc.c2[s], svs = sc.sv[s];
                #pragma unroll
                for (int r = 0; r < 4; ++r) {
                    float xn = c1s * (pa[r] + pb[r] + b3v) + c2s * xo[r] + svs * nz[r];
                    xo[r] = xn;
                    xw[wn][(l4 * 4 + r) * 32 + l15] = (f16)xn;
                }
            }
        }
        // no barrier: xw is per-wave (lgkmcnt covers own write->read);
        // h1 writes next iter are safe (everyone passed bar2 of this step)
    }
    if (wn == 0 && l15 < 10) {
        #pragma unroll
        for (int r = 0; r < 4; ++r)
            out_x0[(size_t)(row0 + l4 * 4 + r) * INUMD + l15] = xo[r];
    }
}

// ---------------- single-kernel GRU, fp16 MFMA, gates in registers ----------------
__global__ __launch_bounds__(512, 2) void gru_all_kernel(
    const float* __restrict__ x0, const float* __restrict__ cond,
    const float* __restrict__ times,
    const float* __restrict__ sf_w1, const float* __restrict__ sf_b1,
    const float* __restrict__ sf_w2, const float* __restrict__ sf_b2,
    const float* __restrict__ sf_w3, const float* __restrict__ sf_b3,
    const float* __restrict__ h0wp, const float* __restrict__ h0_b,
    const f16* __restrict__ whf16, const float* __restrict__ gru_bh,
    const float* __restrict__ gru_wi, const float* __restrict__ gru_bi,
    const float* __restrict__ hd_w, const float* __restrict__ hd_b,
    float* __restrict__ pred, float* __restrict__ stopl)
{
    __shared__ __align__(16) f16 hl[2][32 * 128];   // swizzled, row stride 256B
    __shared__ float dl[32 * 66];
    __shared__ __align__(16) float scratch[3840];
    __shared__ float wis[384], bis[384], bhs[384];
    __shared__ float headp[2][32 * 8];
    int tid = threadIdx.x;
    int row0 = blockIdx.x * 32;
    int lane = tid & 63, wave = tid >> 6;
    int mr = wave >> 2, wn = wave & 3;
    int l15 = lane & 15, l4 = lane >> 4;

    if (tid < 384) { wis[tid] = gru_wi[tid]; bis[tid] = gru_bi[tid]; bhs[tid] = gru_bh[tid]; }
    float* tb = scratch;   // [32][64]
    for (int u = tid; u < 2048; u += 512) {
        int r = u >> 6, k = u & 63;
        tb[u] = times[(size_t)(row0 + r) * TMAXN + k];
    }
    __syncthreads();
    float dtmp[5]; int c = 0;
    for (int idx = tid; idx < 2080; idx += 512) {
        int r = idx / 65, i = idx % 65;
        float v;
        if (i == 0) v = 0.f;
        else if (i == 1) v = tb[r * 64];
        else v = tb[r * 64 + i - 1] - tb[r * 64 + i - 2];
        dtmp[c++] = v;
    }
    __syncthreads();
    c = 0;
    for (int idx = tid; idx < 2080; idx += 512) {
        int r = idx / 65, i = idx % 65;
        dl[r * 66 + i] = dtmp[c++];
    }
    float* in2 = scratch;            // [32][76]
    float* sbuf = scratch + 32 * 76; // [32][44]
    for (int idx = tid; idx < 2048; idx += 512) {
        int r = idx >> 6, k = idx & 63;
        in2[r * 76 + k] = cond[(size_t)(row0 + r) * CONDD + k];
    }
    for (int idx = tid; idx < 320; idx += 512) {
        int r = idx / 10, k = idx % 10;
        in2[r * 76 + 64 + k] = x0[(size_t)(row0 + r) * 10 + k];
    }
    if (tid < 64) { int r = tid >> 1; in2[r * 76 + 74 + (tid & 1)] = 0.f; }
    __syncthreads();
    for (int idx = tid; idx < 640; idx += 512) {
        int r = idx / 20, j = idx % 20;
        float a = sf_b1[j];
        for (int k = 0; k < 10; ++k) a += in2[r * 76 + 64 + k] * sf_w1[j * 10 + k];
        sbuf[r * 44 + j] = fmaxf(a, 0.f);
    }
    __syncthreads();
    for (int idx = tid; idx < 640; idx += 512) {
        int r = idx / 20, j = idx % 20;
        float a = sf_b2[j];
        for (int k = 0; k < 20; ++k) a += sbuf[r * 44 + k] * sf_w2[j * 20 + k];
        sbuf[r * 44 + 22 + j] = fmaxf(a, 0.f);
    }
    __syncthreads();
    for (int idx = tid; idx < 320; idx += 512) {
        int r = idx / 10, j = idx % 10;
        float a = sf_b3[j];
        for (int k = 0; k < 20; ++k) a += sbuf[r * 44 + 22 + k] * sf_w3[j * 20 + k];
        in2[r * 76 + 64 + j] = a;
    }
    __syncthreads();
    for (int idx = tid; idx < 4096; idx += 512) {
        int r = idx >> 7, j = idx & 127;
        float a = h0_b[j];
        const f4* wr = (const f4*)(h0wp + j * 76);
        const f4* iv = (const f4*)(in2 + r * 76);
        #pragma unroll
        for (int q = 0; q < 19; ++q) {
            f4 w = wr[q], v = iv[q];
            a += v[0] * w[0] + v[1] * w[1] + v[2] * w[2] + v[3] * w[3];
        }
        *(f16*)((char*)hl[0] + ((r * 256 + j * 2) ^ ((r & 7) << 4))) = (f16)ftanh(a);
    }
    __syncthreads();

    f16x8 BW[3][2][4];
    float wi_[3][2], bi_[3][2], bh_[3][2], hw0[2], hw1[2];
    #pragma unroll
    for (int g = 0; g < 3; ++g)
        #pragma unroll
        for (int ct = 0; ct < 2; ++ct) {
            int jc = wn * 32 + ct * 16 + l15;
            int col = g * 128 + jc;
            #pragma unroll
            for (int kb = 0; kb < 4; ++kb)
                BW[g][ct][kb] = *(const f16x8*)(whf16 + col * 128 + kb * 32 + l4 * 8);
            wi_[g][ct] = wis[col]; bi_[g][ct] = bis[col]; bh_[g][ct] = bhs[col];
            if (g == 0) { hw0[ct] = hd_w[jc]; hw1[ct] = hd_w[128 + jc]; }
        }
    float hreg[2][4];
    #pragma unroll
    for (int ct = 0; ct < 2; ++ct)
        #pragma unroll
        for (int r = 0; r < 4; ++r) {
            int row = mr * 16 + l4 * 4 + r;
            int jc = wn * 32 + ct * 16 + l15;
            hreg[ct][r] = (float)(*(const f16*)((const char*)hl[0] + ((row * 256 + jc * 2) ^ ((row & 7) << 4))));
        }
    int arow = mr * 16 + l15;
    int aswz = (arow & 7) << 4;

    #pragma unroll 1
    for (int s = 0; s < TMAXN + 1; ++s) {
        const f16* cur = hl[s & 1];
        f16* nxt = hl[(s + 1) & 1];
        f16x8 A[4];
        #pragma unroll
        for (int kb = 0; kb < 4; ++kb)
            A[kb] = *(const f16x8*)((const char*)cur + ((arow * 256 + kb * 64 + l4 * 16) ^ aswz));
        f32x4 acc[3][2];
        #pragma unroll
        for (int g = 0; g < 3; ++g)
            #pragma unroll
            for (int ct = 0; ct < 2; ++ct) {
                f32x4 ci; ci[0] = ci[1] = ci[2] = ci[3] = bh_[g][ct];
                acc[g][ct] = ci;
            }
        #pragma unroll
        for (int kb = 0; kb < 4; ++kb)
            #pragma unroll
            for (int g = 0; g < 3; ++g)
                #pragma unroll
                for (int ct = 0; ct < 2; ++ct)
                    acc[g][ct] = __builtin_amdgcn_mfma_f32_16x16x32_f16(A[kb], BW[g][ct][kb], acc[g][ct], 0, 0, 0);
        float p0[4], p1[4];
        #pragma unroll
        for (int r = 0; r < 4; ++r) {
            int row = mr * 16 + l4 * 4 + r;
            float xv = dl[row * 66 + s];
            p0[r] = 0.f; p1[r] = 0.f;
            #pragma unroll
            for (int ct = 0; ct < 2; ++ct) {
                float rr = fsig(xv * wi_[0][ct] + bi_[0][ct] + acc[0][ct][r]);
                float zz = fsig(xv * wi_[1][ct] + bi_[1][ct] + acc[1][ct][r]);
                float nn = ftanh(xv * wi_[2][ct] + bi_[2][ct] + rr * acc[2][ct][r]);
                float hn = (1.f - zz) * nn + zz * hreg[ct][r];
                hreg[ct][r] = hn;
                int jc = wn * 32 + ct * 16 + l15;
                *(f16*)((char*)nxt + ((row * 256 + jc * 2) ^ ((row & 7) << 4))) = (f16)hn;
                p0[r] += hn * hw0[ct];
                p1[r] += hn * hw1[ct];
            }
        }
        #pragma unroll
        for (int r = 0; r < 4; ++r) {
            #pragma unroll
            for (int off = 1; off < 16; off <<= 1) {
                p0[r] += __shfl_xor(p0[r], off);
                p1[r] += __shfl_xor(p1[r], off);
            }
        }
        if (l15 == 0) {
            #pragma unroll
            for (int r = 0; r < 4; ++r) {
                int row = mr * 16 + l4 * 4 + r;
                headp[s & 1][row * 8 + wn] = p0[r];
                headp[s & 1][row * 8 + 4 + wn] = p1[r];
            }
        }
        __syncthreads();
        if (tid < 64) {
            int r = tid >> 1, o = tid & 1;
            const float* hp = &headp[s & 1][r * 8 + o * 4];
            float v = hd_b[o] + hp[0] + hp[1] + hp[2] + hp[3];
            float* dst = o ? stopl : pred;
            dst[(size_t)(row0 + r) * (TMAXN + 1) + s] = v;
        }
    }
}

extern "C" void kernel_launch(void* const* d_in, const int* in_sizes, int n_in,
                              void* d_out, int out_size, void* d_ws, size_t ws_size,
                              hipStream_t stream)
{
    const float* bert       = (const float*)d_in[0];
    const float* times      = (const float*)d_in[1];
    const float* init_noise = (const float*)d_in[2];
    const float* step_noise = (const float*)d_in[3];
    const float* bp_w  = (const float*)d_in[4];
    const float* bp_b  = (const float*)d_in[5];
    const float* ln_g  = (const float*)d_in[6];
    const float* ln_b  = (const float*)d_in[7];
    const float* tp_w1 = (const float*)d_in[8];
    const float* tp_b1 = (const float*)d_in[9];
    const float* tp_w2 = (const float*)d_in[10];
    const float* tp_b2 = (const float*)d_in[11];
    const float* dn_w1 = (const float*)d_in[12];
    const float* dn_b1 = (const float*)d_in[13];
    const float* dn_w2 = (const float*)d_in[14];
    const float* dn_b2 = (const float*)d_in[15];
    const float* dn_w3 = (const float*)d_in[16];
    const float* dn_b3 = (const float*)d_in[17];
    const float* sf_w1 = (const float*)d_in[18];
    const float* sf_b1 = (const float*)d_in[19];
    const float* sf_w2 = (const float*)d_in[20];
    const float* sf_b2 = (const float*)d_in[21];
    const float* sf_w3 = (const float*)d_in[22];
    const float* sf_b3 = (const float*)d_in[23];
    const float* h0_w  = (const float*)d_in[24];
    const float* h0_b  = (const float*)d_in[25];
    const float* gru_wi = (const float*)d_in[26];
    const float* gru_bi = (const float*)d_in[27];
    const float* gru_wh = (const float*)d_in[28];
    const float* gru_bh = (const float*)d_in[29];
    const float* hd_w   = (const float*)d_in[30];
    const float* hd_b   = (const float*)d_in[31];

    float* ws    = (float*)d_ws;
    float* cond  = ws;                          // B*64
    float* te    = cond + (size_t)NB * CONDD;   // 50*64
    float* b1eff = te + SAMPLE_TN * TEMBD;      // 50*256
    float* w1ct  = b1eff + SAMPLE_TN * 256;     // 64*256 (fp32, k-major)
    float* h0wp  = w1ct + 64 * 256;             // 128*76
    float* bp_wt = h0wp + 128 * 76;             // 768*64
    f16*   w1x16 = (f16*)(bp_wt + 768 * 64);    // 256*32 f16
    f16*   w2f16 = w1x16 + 256 * 32;            // 256*256 f16
    f16*   whf16 = w2f16 + 256 * 256;           // 384*128 f16
    f16*   w3f16 = whf16 + 384 * 128;           // 16*256 f16 (zero-padded rows 10..15)

    double ab[TDIFFN + 1];
    for (int i = 0; i <= TDIFFN; ++i) {
        double xx = (double)i / (double)TDIFFN;
        double v = cos((xx + 0.008) / 1.008 * M_PI * 0.5);
        ab[i] = v * v;
    }
    double ab0 = ab[0];
    for (int i = 0; i <= TDIFFN; ++i) ab[i] /= ab0;
    double betas[TDIFFN], alphas[TDIFFN], abar[TDIFFN];
    double cp = 1.0;
    for (int i = 0; i < TDIFFN; ++i) {
        double b = 1.0 - ab[i + 1] / ab[i];
        if (b > 0.9999) b = 0.9999;
        betas[i] = b; alphas[i] = 1.0 - b;
        cp *= alphas[i]; abar[i] = cp;
    }
    Sched sc;
    for (int s = 0; s < SAMPLE_TN; ++s) {
        int tt = TDIFFN - 1 - 4 * s;
        double abt = abar[tt];
        double abp = (tt > 0) ? abar[tt - 1] : 1.0;
        double beta = betas[tt];
        sc.c1[s] = (float)(sqrt(abp) * beta / (1.0 - abt));
        sc.c2[s] = (float)(sqrt(alphas[tt]) * (1.0 - abp) / (1.0 - abt));
        sc.sv[s] = (float)((tt > 0) ? sqrt((1.0 - abp) / (1.0 - abt) * beta) : 0.0);
        sc.ts[s] = (float)tt;
    }

    float* out    = (float*)d_out;
    float* out_x0 = out;
    float* pred   = out + (size_t)NB * INUMD;
    float* stopl  = pred + (size_t)NB * (TMAXN + 1);

    pack_kernel<<<256, 256, 0, stream>>>(dn_w1, dn_w2, dn_w3, gru_wh, h0_w, bp_w,
                                         w1ct, w1x16, w2f16, whf16, h0wp, bp_wt, w3f16);
    bert2_kernel<<<NB / 64, 512, 0, stream>>>(bert, bp_wt, bp_b, ln_g, ln_b, cond);
    te_kernel<<<SAMPLE_TN, 128, 0, stream>>>(tp_w1, tp_b1, tp_w2, tp_b2, te, sc);
    b1eff_kernel<<<SAMPLE_TN, 256, 0, stream>>>(te, dn_w1, dn_b1, b1eff);

    ddpm_all_kernel<<<NB / 16, 256, 0, stream>>>(
        init_noise, cond, step_noise, w1ct, w1x16, b1eff, w2f16, dn_b2, w3f16, dn_b3,
        sc, out_x0);

    gru_all_kernel<<<NB / 32, 512, 0, stream>>>(
        out_x0, cond, times,
        sf_w1, sf_b1, sf_w2, sf_b2, sf_w3, sf_b3,
        h0wp, h0_b, whf16, gru_bh, gru_wi, gru_bi, hd_w, hd_b,
        pred, stopl);
}